// Round 8
// baseline (603.644 us; speedup 1.0000x reference)
//
#include <hip/hip_runtime.h>
#include <math.h>

#define DD 128
#define NEG 0.2f

typedef short short8 __attribute__((ext_vector_type(8)));
typedef float f32x4 __attribute__((ext_vector_type(4)));
typedef float f32x2 __attribute__((ext_vector_type(2)));
typedef _Float16 h2v __attribute__((ext_vector_type(2)));

__device__ __forceinline__ unsigned short f2bf(float f) {
    unsigned u = __float_as_uint(f);
    return (unsigned short)((u + 0x7fffu + ((u >> 16) & 1u)) >> 16);
}
__device__ __forceinline__ float bf2f(unsigned short h) {
    return __uint_as_float(((unsigned)h) << 16);
}

#if __has_builtin(__builtin_amdgcn_exp2f)
#define EXP2F(x) __builtin_amdgcn_exp2f(x)
#else
#define EXP2F(x) exp2f(x)
#endif

// ---------------- CSR build, direct-atomic version ----------------
// r7 post-mortem: the old two-level partition (histC/part3/part4) cost ~160us
// (part3: 81KB LDS -> 1 block/CU, latency-bound single pass + 25MB part[]
// round-trip). Contention here is only ~16 atomics/address over 100k addresses
// (deg[] 400KB and srcs[] 6.4MB are L2-resident), unlike round-2's 2500-way
// hot-bin disaster -> direct atomic build is fine.

// deg histogram over dst (+ fused weight cast in blocks >= EB)
__global__ __launch_bounds__(256) void k_deg(const int* __restrict__ dst,
                                             int* __restrict__ deg, int E, int EB,
                                             const float* __restrict__ Wl,
                                             const float* __restrict__ Wr,
                                             unsigned short* __restrict__ Wth,
                                             unsigned short* __restrict__ Wtl) {
    int b = blockIdx.x;
    int t = threadIdx.x;
    if (b >= EB) {
        int idx = (b - EB) * 256 + t;
        if (idx < 3 * 256 * 128) {
            int L = idx >> 15;
            int rem = idx & 32767;
            int nn = rem >> 7;
            int k = rem & 127;
            float v = (nn < 128) ? Wl[L * 16384 + k * 128 + nn]
                                 : Wr[L * 16384 + k * 128 + (nn - 128)];
            unsigned short hh = f2bf(v);
            Wth[idx] = hh;
            Wtl[idx] = f2bf(v - bf2f(hh));
        }
        return;
    }
    int stride = EB * 256;
    for (int i = b * 256 + t; i < E; i += stride)
        atomicAdd(&deg[dst[i]], 1);
}

// two-pass scan of deg[N] -> row_ptr[N+1], cursor[N]
#define SCH 2048
__global__ __launch_bounds__(256) void k_scanA(const int* __restrict__ deg,
                                               int* __restrict__ csum, int N) {
    __shared__ int red[256];
    int t = threadIdx.x;
    int c0 = blockIdx.x * SCH;
    int s = 0;
#pragma unroll
    for (int j = 0; j < 8; j++) {
        int i = c0 + j * 256 + t;
        s += (i < N) ? deg[i] : 0;
    }
    red[t] = s;
    __syncthreads();
    for (int off = 128; off > 0; off >>= 1) {
        if (t < off) red[t] += red[t + off];
        __syncthreads();
    }
    if (t == 0) csum[blockIdx.x] = red[0];
}

// local scan + global base; also folds in the 128-bin degree histogram
// (deghist kernel deleted).
__global__ __launch_bounds__(256) void k_scanC(const int* __restrict__ deg,
                                               const int* __restrict__ csum,
                                               int* __restrict__ row_ptr,
                                               int* __restrict__ cursor,
                                               int* __restrict__ histD,
                                               int N, int E, int NSC) {
    __shared__ int cb[128];
    __shared__ int aux[256];
    __shared__ int hl[128];
    int t = threadIdx.x;
    int b = blockIdx.x;
    if (t < 128) { cb[t] = (t < NSC) ? csum[t] : 0; hl[t] = 0; }
    __syncthreads();
    for (int off = 1; off < 128; off <<= 1) {
        int v = 0;
        if (t < 128 && t >= off) v = cb[t - off];
        __syncthreads();
        if (t < 128) cb[t] += v;
        __syncthreads();
    }
    int cbase = b ? cb[b - 1] : 0;

    int base = b * SCH + t * 8;
    int v[8];
    int s = 0;
#pragma unroll
    for (int j = 0; j < 8; j++) {
        int i = base + j;
        int x = (i < N) ? deg[i] : 0;
        if (i < N) atomicAdd(&hl[x < 127 ? x : 127], 1);
        v[j] = s;
        s += x;
    }
    aux[t] = s;
    __syncthreads();
    for (int off = 1; off < 256; off <<= 1) {
        int w = (t >= off) ? aux[t - off] : 0;
        __syncthreads();
        aux[t] += w;
        __syncthreads();
    }
    int off0 = cbase + aux[t] - s;
#pragma unroll
    for (int j = 0; j < 8; j++) {
        int i = base + j;
        if (i < N) {
            int r = off0 + v[j];
            row_ptr[i] = r;
            cursor[i] = r;
        }
    }
    __syncthreads();
    if (t < 128 && hl[t]) atomicAdd(&histD[t], hl[t]);
    if (b == 0 && t == 0) row_ptr[N] = E;
}

// edge scatter (+ fused degree-bucket partition in blocks >= EB)
#define NCH 8192
__global__ __launch_bounds__(256) void k_scatter(const int* __restrict__ srcI,
                                                 const int* __restrict__ dstI,
                                                 int* __restrict__ cursor,
                                                 int* __restrict__ srcs,
                                                 int E, int EB,
                                                 const int* __restrict__ deg,
                                                 const int* __restrict__ histD,
                                                 int* __restrict__ cursor0D,
                                                 int* __restrict__ order, int N) {
    __shared__ int hist[128];
    __shared__ int gex[128];
    __shared__ int excl[128];
    __shared__ int cur[128];
    __shared__ int resB[128];
    __shared__ int stage[NCH];
    int t = threadIdx.x;
    int b = blockIdx.x;

    if (b < EB) {
        int stride = EB * 256;
        for (int i = b * 256 + t; i < E; i += stride) {
            int d = dstI[i];
            int pos = atomicAdd(&cursor[d], 1);
            srcs[pos] = srcI[i];
        }
        return;
    }

    // ---- degree-bucket partition (one chunk of NCH nodes per block) ----
    int db = b - EB;
    int c0 = db * NCH;
    int cnt = N - c0; if (cnt > NCH) cnt = NCH;

    int g0 = 0;
    if (t < 128) { hist[t] = 0; g0 = histD[t]; gex[t] = g0; }
    __syncthreads();
    for (int i = t; i < cnt; i += 256) {
        int dg = deg[c0 + i];
        int c = dg < 127 ? dg : 127;
        atomicAdd(&hist[c], 1);
    }
    __syncthreads();
    for (int off = 1; off < 128; off <<= 1) {
        int v = 0;
        if (t < 128 && t >= off) v = gex[t - off];
        __syncthreads();
        if (t < 128) gex[t] += v;
        __syncthreads();
    }
    if (t < 128) resB[t] = (gex[t] - g0) + (hist[t] ? atomicAdd(&cursor0D[t], hist[t]) : 0);
    if (t < 128) excl[t] = hist[t];
    __syncthreads();
    for (int off = 1; off < 128; off <<= 1) {
        int v = 0;
        if (t < 128 && t >= off) v = excl[t - off];
        __syncthreads();
        if (t < 128) excl[t] += v;
        __syncthreads();
    }
    if (t < 128) { excl[t] -= hist[t]; cur[t] = excl[t]; }
    __syncthreads();
    for (int i = t; i < cnt; i += 256) {
        int dg = deg[c0 + i];
        int c = dg < 127 ? dg : 127;
        int p = atomicAdd(&cur[c], 1);
        stage[p] = (c << 20) | (c0 + i);   // N < 2^20
    }
    __syncthreads();
    for (int i = t; i < cnt; i += 256) {
        int v = stage[i];
        int c = v >> 20;
        order[resB[c] + (i - excl[c])] = v & 0xFFFFF;
    }
}

// ---------------- MFMA GEMM: [xl|xr][M,128each] = A[M,128] @ W[128,256] ----------------
// Proven LDS structure + T14 prefetch; XCD-paired 1D grid (j, j+8 share an XCD
// -> A-tile shared through L2); F32SRC=1 stages layer 0 directly from x (f32)
// with in-register hi/lo split (bit-identical to the old castx).
__device__ __forceinline__ void cvt8(const float4& a, const float4& b, uint4& hi, uint4& lo) {
    union US8 { unsigned short s[8]; uint4 u; } H, Lo;
    float f[8] = {a.x, a.y, a.z, a.w, b.x, b.y, b.z, b.w};
#pragma unroll
    for (int i = 0; i < 8; i++) {
        unsigned short h = f2bf(f[i]);
        H.s[i] = h;
        Lo.s[i] = f2bf(f[i] - bf2f(h));
    }
    hi = H.u; lo = Lo.u;
}

template <int F32SRC>
__global__ __launch_bounds__(256) void k_gemm(const float* __restrict__ Xf,
                                              const unsigned short* __restrict__ Ahi,
                                              const unsigned short* __restrict__ Alo,
                                              const unsigned short* __restrict__ Wth,
                                              const unsigned short* __restrict__ Wtl,
                                              _Float16* __restrict__ xl, _Float16* __restrict__ xr,
                                              int M, int L, int gX) {
    __shared__ unsigned short sA[2][128][40];
    __shared__ unsigned short sB[2][128][40];
    int b = blockIdx.x;
    int grp = b >> 4, j8 = b & 7, half = (b >> 3) & 1;
    int ry = grp * 8 + j8;
    if (ry >= gX) return;

    int t = threadIdx.x;
    int lane = t & 63;
    int l15 = lane & 15;
    int quad = lane >> 4;
    int wave = t >> 6;
    int wm = wave & 1;
    int wn = wave >> 1;
    int r0 = ry * 128;
    const unsigned short* WthL = Wth + ((size_t)L * 256 + half * 128) * 128;
    const unsigned short* WtlL = Wtl + ((size_t)L * 256 + half * 128) * 128;

    int row0 = t >> 2,       row1 = (t + 256) >> 2;
    int kq   = (t & 3) * 8;
    int gr0 = r0 + row0; gr0 = gr0 < M ? gr0 : M - 1;
    int gr1 = r0 + row1; gr1 = gr1 < M ? gr1 : M - 1;

    uint4 rAh0, rAh1, rAl0, rAl1, rBh0, rBh1, rBl0, rBl1;
    float4 f00, f01, f10, f11;

#define GLOADA(K0)                                                          \
    if (F32SRC) {                                                           \
        f00 = *(const float4*)(Xf + (size_t)gr0 * DD + (K0) + kq);          \
        f01 = *(const float4*)(Xf + (size_t)gr0 * DD + (K0) + kq + 4);      \
        f10 = *(const float4*)(Xf + (size_t)gr1 * DD + (K0) + kq);          \
        f11 = *(const float4*)(Xf + (size_t)gr1 * DD + (K0) + kq + 4);      \
    } else {                                                                \
        rAh0 = *(const uint4*)(Ahi + (size_t)gr0 * DD + (K0) + kq);         \
        rAh1 = *(const uint4*)(Ahi + (size_t)gr1 * DD + (K0) + kq);         \
        rAl0 = *(const uint4*)(Alo + (size_t)gr0 * DD + (K0) + kq);         \
        rAl1 = *(const uint4*)(Alo + (size_t)gr1 * DD + (K0) + kq);         \
    }
#define GLOADB(K0)                                                          \
    rBh0 = *(const uint4*)(WthL + (size_t)row0 * DD + (K0) + kq);           \
    rBh1 = *(const uint4*)(WthL + (size_t)row1 * DD + (K0) + kq);           \
    rBl0 = *(const uint4*)(WtlL + (size_t)row0 * DD + (K0) + kq);           \
    rBl1 = *(const uint4*)(WtlL + (size_t)row1 * DD + (K0) + kq);

    f32x4 acc[4][4] = {};
    union F8 { short8 v; uint4 u; };

    GLOADA(0);
    GLOADB(0);

#pragma unroll
    for (int kc = 0; kc < 4; kc++) {
        if (kc) __syncthreads();
        if (F32SRC) {
            cvt8(f00, f01, rAh0, rAl0);
            cvt8(f10, f11, rAh1, rAl1);
        }
        *(uint4*)&sA[0][row0][kq] = rAh0;
        *(uint4*)&sA[0][row1][kq] = rAh1;
        *(uint4*)&sA[1][row0][kq] = rAl0;
        *(uint4*)&sA[1][row1][kq] = rAl1;
        *(uint4*)&sB[0][row0][kq] = rBh0;
        *(uint4*)&sB[0][row1][kq] = rBh1;
        *(uint4*)&sB[1][row0][kq] = rBl0;
        *(uint4*)&sB[1][row1][kq] = rBl1;
        __syncthreads();
        if (kc < 3) { GLOADA((kc + 1) * 32); GLOADB((kc + 1) * 32); }  // T14

        F8 ah[4], al[4], bh[4], bl[4];
#pragma unroll
        for (int mt = 0; mt < 4; mt++) {
            ah[mt].u = *(const uint4*)&sA[0][wm * 64 + mt * 16 + l15][quad * 8];
            al[mt].u = *(const uint4*)&sA[1][wm * 64 + mt * 16 + l15][quad * 8];
        }
#pragma unroll
        for (int nt = 0; nt < 4; nt++) {
            bh[nt].u = *(const uint4*)&sB[0][wn * 64 + nt * 16 + l15][quad * 8];
            bl[nt].u = *(const uint4*)&sB[1][wn * 64 + nt * 16 + l15][quad * 8];
        }
#pragma unroll
        for (int mt = 0; mt < 4; mt++)
#pragma unroll
            for (int nt = 0; nt < 4; nt++) {
                acc[mt][nt] = __builtin_amdgcn_mfma_f32_16x16x32_bf16(ah[mt].v, bh[nt].v, acc[mt][nt], 0, 0, 0);
                acc[mt][nt] = __builtin_amdgcn_mfma_f32_16x16x32_bf16(al[mt].v, bh[nt].v, acc[mt][nt], 0, 0, 0);
                acc[mt][nt] = __builtin_amdgcn_mfma_f32_16x16x32_bf16(ah[mt].v, bl[nt].v, acc[mt][nt], 0, 0, 0);
            }
    }
#undef GLOADA
#undef GLOADB

    _Float16* C = half ? xr : xl;
#pragma unroll
    for (int mt = 0; mt < 4; mt++)
#pragma unroll
        for (int r = 0; r < 4; r++) {
            int row = r0 + wm * 64 + mt * 16 + quad * 4 + r;
            if (row < M) {
#pragma unroll
                for (int nt = 0; nt < 4; nt++)
                    C[(size_t)row * DD + wn * 64 + nt * 16 + l15] = (_Float16)acc[mt][nt][r];
            }
        }
}

// ---------------- fused per-dst attention + aggregate ----------------
// NOTE (r5/r6): pinned at random-gather cache bandwidth (~3.6 TB/s TCC);
// multiple structural variants all land at ~70us with FETCH ~200MB. Frozen.
__global__ __launch_bounds__(256) void k_attn(const _Float16* __restrict__ xl,
                                              const _Float16* __restrict__ xr,
                                              const int* __restrict__ row_ptr,
                                              const int* __restrict__ srcs,
                                              const int* __restrict__ order,
                                              const float* __restrict__ att,
                                              const float* __restrict__ bias,
                                              float* __restrict__ outF,
                                              unsigned short* __restrict__ outHi,
                                              unsigned short* __restrict__ outLo,
                                              int n, int mode) {
    int wid = (blockIdx.x * blockDim.x + threadIdx.x) >> 6;
    int l = threadIdx.x & 63;
    int l15 = l & 15;
    int g = l >> 4;
    int idx = wid * 4 + g;
    bool act = idx < n;
    int d = act ? order[idx] : 0;

    union Q { uint4 q; h2v h[4]; };
    const float LOG2E = 1.44269504088896f;

    h2v at[4], xrh[4];
    {
        float4 a0 = *(const float4*)(att + l15 * 8);
        float4 a1 = *(const float4*)(att + l15 * 8 + 4);
        at[0] = h2v{(_Float16)(a0.x * LOG2E), (_Float16)(a0.y * LOG2E)};
        at[1] = h2v{(_Float16)(a0.z * LOG2E), (_Float16)(a0.w * LOG2E)};
        at[2] = h2v{(_Float16)(a1.x * LOG2E), (_Float16)(a1.y * LOG2E)};
        at[3] = h2v{(_Float16)(a1.z * LOG2E), (_Float16)(a1.w * LOG2E)};
        Q hr; hr.q = *(const uint4*)(xr + (size_t)d * DD + l15 * 8);
#pragma unroll
        for (int j = 0; j < 4; j++) xrh[j] = hr.h[j];
    }
    const _Float16 cneg = (_Float16)NEG;

    int beg = act ? row_ptr[d] : 0;
    int end = act ? row_ptr[d + 1] : 0;
    int cnt = end - beg;

    int mc = cnt;
    mc = max(mc, __shfl_xor(mc, 16, 64));
    mc = max(mc, __shfl_xor(mc, 32, 64));
    int iters = (mc + 3) >> 2;

    float lse = 0.f;
    float av[8] = {};

    int i0 = beg, i1 = beg + 1, i2 = beg + 2, i3 = beg + 3;
    bool v0 = i0 < end, v1 = i1 < end, v2 = i2 < end, v3 = i3 < end;
    int s0 = v0 ? srcs[i0] : 0;
    int s1 = v1 ? srcs[i1] : 0;
    int s2 = v2 ? srcs[i2] : 0;
    int s3 = v3 ? srcs[i3] : 0;

    const _Float16* xlp = xl + l15 * 8;

    for (int it = 0; it < iters; ++it) {
        Q h0, h1, h2, h3;
        h0.q = *(const uint4*)(xlp + (size_t)s0 * DD);
        h1.q = *(const uint4*)(xlp + (size_t)s1 * DD);
        h2.q = *(const uint4*)(xlp + (size_t)s2 * DD);
        h3.q = *(const uint4*)(xlp + (size_t)s3 * DD);
        int n0 = i0 + 4, n1 = i1 + 4, n2 = i2 + 4, n3 = i3 + 4;
        bool nv0 = n0 < end, nv1 = n1 < end, nv2 = n2 < end, nv3 = n3 < end;
        int t0 = nv0 ? srcs[n0] : 0;
        int t1 = nv1 ? srcs[n1] : 0;
        int t2 = nv2 ? srcs[n2] : 0;
        int t3 = nv3 ? srcs[n3] : 0;

        float p0 = 0.f, p1 = 0.f, p2 = 0.f, p3 = 0.f;
#pragma unroll
        for (int j = 0; j < 4; j++) {
            h2v z0 = h0.h[j] + xrh[j];
            h2v zl0 = __builtin_elementwise_max(z0, z0 * cneg);
            p0 = __builtin_amdgcn_fdot2(zl0, at[j], p0, false);
            h2v z1 = h1.h[j] + xrh[j];
            h2v zl1 = __builtin_elementwise_max(z1, z1 * cneg);
            p1 = __builtin_amdgcn_fdot2(zl1, at[j], p1, false);
            h2v z2 = h2.h[j] + xrh[j];
            h2v zl2 = __builtin_elementwise_max(z2, z2 * cneg);
            p2 = __builtin_amdgcn_fdot2(zl2, at[j], p2, false);
            h2v z3 = h3.h[j] + xrh[j];
            h2v zl3 = __builtin_elementwise_max(z3, z3 * cneg);
            p3 = __builtin_amdgcn_fdot2(zl3, at[j], p3, false);
        }
        p0 += __shfl_xor(p0, 1, 64);  p1 += __shfl_xor(p1, 1, 64);
        p2 += __shfl_xor(p2, 1, 64);  p3 += __shfl_xor(p3, 1, 64);
        p0 += __shfl_xor(p0, 2, 64);  p1 += __shfl_xor(p1, 2, 64);
        p2 += __shfl_xor(p2, 2, 64);  p3 += __shfl_xor(p3, 2, 64);
        p0 += __shfl_xor(p0, 4, 64);  p1 += __shfl_xor(p1, 4, 64);
        p2 += __shfl_xor(p2, 4, 64);  p3 += __shfl_xor(p3, 4, 64);
        p0 += __shfl_xor(p0, 8, 64);  p1 += __shfl_xor(p1, 8, 64);
        p2 += __shfl_xor(p2, 8, 64);  p3 += __shfl_xor(p3, 8, 64);
        p0 = fminf(fmaxf(p0, -86.f), 86.f);
        p1 = fminf(fmaxf(p1, -86.f), 86.f);
        p2 = fminf(fmaxf(p2, -86.f), 86.f);
        p3 = fminf(fmaxf(p3, -86.f), 86.f);
        float w0 = v0 ? EXP2F(p0) : 0.f;
        float w1 = v1 ? EXP2F(p1) : 0.f;
        float w2 = v2 ? EXP2F(p2) : 0.f;
        float w3 = v3 ? EXP2F(p3) : 0.f;
        lse += (w0 + w1) + (w2 + w3);
#pragma unroll
        for (int j = 0; j < 4; j++) {
            av[2 * j]     += (float)h0.h[j][0] * w0;
            av[2 * j + 1] += (float)h0.h[j][1] * w0;
            av[2 * j]     += (float)h1.h[j][0] * w1;
            av[2 * j + 1] += (float)h1.h[j][1] * w1;
            av[2 * j]     += (float)h2.h[j][0] * w2;
            av[2 * j + 1] += (float)h2.h[j][1] * w2;
            av[2 * j]     += (float)h3.h[j][0] * w3;
            av[2 * j + 1] += (float)h3.h[j][1] * w3;
        }
        i0 = n0; i1 = n1; i2 = n2; i3 = n3;
        v0 = nv0; v1 = nv1; v2 = nv2; v3 = nv3;
        s0 = t0; s1 = t1; s2 = t2; s3 = t3;
    }

    if (act) {
        float inv = (cnt > 0) ? 1.0f / lse : 0.f;
        float o[8];
        float4 b0 = *(const float4*)(bias + l15 * 8);
        float4 b1 = *(const float4*)(bias + l15 * 8 + 4);
        float bv[8] = {b0.x, b0.y, b0.z, b0.w, b1.x, b1.y, b1.z, b1.w};
#pragma unroll
        for (int j = 0; j < 8; j++) o[j] = av[j] * inv + bv[j];
        if (mode) {
            union U8 { unsigned short s[8]; uint4 q; };
            U8 hh, ll;
#pragma unroll
            for (int j = 0; j < 8; j++) {
                float v = fmaxf(o[j], 0.f);
                hh.s[j] = f2bf(v);
                ll.s[j] = f2bf(v - bf2f(hh.s[j]));
            }
            *(uint4*)(outHi + (size_t)d * DD + l15 * 8) = hh.q;
            *(uint4*)(outLo + (size_t)d * DD + l15 * 8) = ll.q;
        } else {
            float4 o0 = {o[0], o[1], o[2], o[3]};
            float4 o1 = {o[4], o[5], o[6], o[7]};
            float* op = outF + (size_t)d * DD + l15 * 8;
            *(float4*)op = o0;
            *(float4*)(op + 4) = o1;
        }
    }
}

// ---------------- launch ----------------
extern "C" void kernel_launch(void* const* d_in, const int* in_sizes, int n_in,
                              void* d_out, int out_size, void* d_ws, size_t ws_size,
                              hipStream_t stream) {
    const float* x    = (const float*)d_in[0];
    const float* Wl   = (const float*)d_in[1];
    const float* Wr   = (const float*)d_in[2];
    const float* att  = (const float*)d_in[3];
    const float* bias = (const float*)d_in[4];
    const int*   ei   = (const int*)d_in[5];

    int N = in_sizes[0] / DD;
    int E = in_sizes[5] / 2;
    const int* srcI = ei;
    const int* dstI = ei + E;
    float* out = (float*)d_out;

    char* ws = (char*)d_ws;
    size_t off = 0;
    auto alloc = [&](size_t bytes) -> void* {
        void* p = ws + off;
        off += (bytes + 255) & ~(size_t)255;
        return p;
    };
    _Float16*       xl   = (_Float16*)alloc((size_t)N * DD * 2);
    _Float16*       xr   = (_Float16*)alloc((size_t)N * DD * 2);
    unsigned short* Ahi  = (unsigned short*)alloc((size_t)N * DD * 2);
    unsigned short* Alo  = (unsigned short*)alloc((size_t)N * DD * 2);
    unsigned short* Wth  = (unsigned short*)alloc((size_t)3 * 256 * 128 * 2);
    unsigned short* Wtl  = (unsigned short*)alloc((size_t)3 * 256 * 128 * 2);
    int*   srcs    = (int*)alloc((size_t)E * 4);
    int*   row_ptr = (int*)alloc((size_t)(N + 1) * 4);
    int*   cursor  = (int*)alloc((size_t)N * 4);
    int*   order   = (int*)alloc((size_t)N * 4);
    int*   csum    = (int*)alloc((size_t)256 * 4);
    // zero-block: deg[N] | histD[128] | cursor0D[128]
    int*   z       = (int*)alloc((size_t)(N + 256) * 4);
    int*   deg      = z;
    int*   histD    = z + N;
    int*   cursor0D = z + N + 128;

    const int tb = 256;
    const int EB = 2048;
    int NSC = (N + SCH - 1) / SCH;       // scan chunks (<=128 for N<=256k)
    int gD  = (N + NCH - 1) / NCH;       // degree-partition chunks

    (void)hipMemsetAsync(z, 0, (size_t)(N + 256) * 4, stream);
    k_deg<<<EB + 384, tb, 0, stream>>>(dstI, deg, E, EB, Wl, Wr, Wth, Wtl);
    k_scanA<<<NSC, tb, 0, stream>>>(deg, csum, N);
    k_scanC<<<NSC, tb, 0, stream>>>(deg, csum, row_ptr, cursor, histD, N, E, NSC);
    k_scatter<<<EB + gD, tb, 0, stream>>>(srcI, dstI, cursor, srcs, E, EB,
                                          deg, histD, cursor0D, order, N);

    int gX = (N + 127) / 128;
    int NB = 16 * ((gX + 7) / 8);   // XCD-paired 1D grid (j and j+8 share an XCD)
    for (int L = 0; L < 3; ++L) {
        if (L == 0)
            k_gemm<1><<<NB, 256, 0, stream>>>(x, Ahi, Alo, Wth, Wtl, xl, xr, N, L, gX);
        else
            k_gemm<0><<<NB, 256, 0, stream>>>(x, Ahi, Alo, Wth, Wtl, xl, xr, N, L, gX);
        k_attn<<<((size_t)N * 16 + tb - 1) / tb, tb, 0, stream>>>(
            xl, xr, row_ptr, srcs, order, att + (size_t)L * DD, bias + (size_t)L * DD,
            out, Ahi, Alo, N, (L < 2) ? 1 : 0);
    }
}

// Round 9
// 488.100 us; speedup vs baseline: 1.2367x; 1.2367x over previous
//
#include <hip/hip_runtime.h>
#include <math.h>

#define DD 128
#define NEG 0.2f

typedef short short8 __attribute__((ext_vector_type(8)));
typedef float f32x4 __attribute__((ext_vector_type(4)));
typedef float f32x2 __attribute__((ext_vector_type(2)));
typedef _Float16 h2v __attribute__((ext_vector_type(2)));

__device__ __forceinline__ unsigned short f2bf(float f) {
    unsigned u = __float_as_uint(f);
    return (unsigned short)((u + 0x7fffu + ((u >> 16) & 1u)) >> 16);
}
__device__ __forceinline__ float bf2f(unsigned short h) {
    return __uint_as_float(((unsigned)h) << 16);
}

#if __has_builtin(__builtin_amdgcn_exp2f)
#define EXP2F(x) __builtin_amdgcn_exp2f(x)
#else
#define EXP2F(x) exp2f(x)
#endif

// ======================= CSR build =======================
// HW lesson (r8): scattered device-scope atomicAdd is memory-side on gfx950 —
// each costs a full 64B HBM RMW (1.6M atomics == 102MB of WRITE_SIZE). LDS
// histogram aggregation is mandatory. Two-level partition retained from r7,
// but WITHOUT the LDS stage buffers: destination ranges are block-private and
// contiguous per bucket, so plain stores coalesce in L2. part3 LDS 81->13KB
// (1 -> ~12 blocks/CU), part4 34->2KB.

// ---------------- fused: global dst-chunk histogram + weight cast ----------------
__global__ __launch_bounds__(256) void k_histC(const int* __restrict__ dst,
                                               int* __restrict__ histC, int E, int CB,
                                               const float* __restrict__ Wl,
                                               const float* __restrict__ Wr,
                                               unsigned short* __restrict__ Wth,
                                               unsigned short* __restrict__ Wtl) {
    __shared__ int h[1024];
    int t = threadIdx.x;
    if (blockIdx.x >= 256) {
        int idx = (blockIdx.x - 256) * 256 + t;
        if (idx < 3 * 256 * 128) {
            int L = idx >> 15;
            int rem = idx & 32767;
            int nn = rem >> 7;
            int k = rem & 127;
            float v = (nn < 128) ? Wl[L * 16384 + k * 128 + nn]
                                 : Wr[L * 16384 + k * 128 + (nn - 128)];
            unsigned short hh = f2bf(v);
            Wth[idx] = hh;
            Wtl[idx] = f2bf(v - bf2f(hh));
        }
        return;
    }
    for (int j = t; j < 1024; j += 256) h[j] = 0;
    __syncthreads();
    int stride = 256 * 256;
    for (int i = blockIdx.x * 256 + t; i < E; i += stride)
        atomicAdd(&h[dst[i] >> 7], 1);
    __syncthreads();
    for (int j = t; j < CB; j += 256)
        if (h[j]) atomicAdd(&histC[j], h[j]);
}

// ---------------- CSR partition pass 1 (stage-free) ----------------
// Each block: LDS hist of its chunk, global reserve (one atomic per bin),
// in-block scan of histC for the global base, then DIRECT scattered stores of
// (src,dst) to part[] — ranges are block-private contiguous per bucket.
#define CHUNK 8192
__global__ __launch_bounds__(256) void k_part3(const int* __restrict__ srcI,
                                               const int* __restrict__ dstI,
                                               const int* __restrict__ histC,
                                               int* __restrict__ cursor0C,
                                               int* __restrict__ baseC,
                                               uint2* __restrict__ part,
                                               int E, int CB) {
    __shared__ int sh[1024];
    __shared__ int gsh[1024];
    __shared__ int aux[256];
    __shared__ int cur[1024];
    int t = threadIdx.x;
    int c0 = blockIdx.x * CHUNK;
    int cnt = E - c0; if (cnt > CHUNK) cnt = CHUNK;

    for (int j = t; j < 1024; j += 256) sh[j] = 0;
    for (int j = t; j < 1024; j += 256) gsh[j] = (j < CB) ? histC[j] : 0;
    __syncthreads();
    for (int i = t; i < cnt; i += 256)
        atomicAdd(&sh[dstI[c0 + i] >> 7], 1);

    // exclusive scan of gsh (histC) — 1024 wide, 4 elems/thread
    __syncthreads();
    {
        int base = t * 4;
        int a0 = gsh[base], a1 = gsh[base + 1], a2 = gsh[base + 2], a3 = gsh[base + 3];
        int s = a0 + a1 + a2 + a3;
        aux[t] = s;
        __syncthreads();
        for (int off = 1; off < 256; off <<= 1) {
            int v = (t >= off) ? aux[t - off] : 0;
            __syncthreads();
            aux[t] += v;
            __syncthreads();
        }
        int excl = aux[t] - s;
        gsh[base] = excl;
        gsh[base + 1] = excl + a0;
        gsh[base + 2] = excl + a0 + a1;
        gsh[base + 3] = excl + a0 + a1 + a2;
        __syncthreads();
    }
    for (int j = t; j < CB; j += 256) {
        int c = sh[j];
        cur[j] = gsh[j] + (c ? atomicAdd(&cursor0C[j], c) : 0);
    }
    if (blockIdx.x == 0)
        for (int j = t; j <= CB; j += 256) baseC[j] = gsh[j];
    __syncthreads();
    for (int i = t; i < cnt; i += 256) {
        unsigned s = (unsigned)srcI[c0 + i];
        unsigned d = (unsigned)dstI[c0 + i];
        int b = (int)(d >> 7);
        int pos = atomicAdd(&cur[b], 1);
        part[pos].x = s;
        part[pos].y = d;
    }
}

// ---------------- CSR partition pass 2 (stage-free) ----------------
__global__ __launch_bounds__(256) void k_part4(const uint2* __restrict__ part,
                                               const int* __restrict__ baseC,
                                               int* __restrict__ srcs,
                                               int* __restrict__ row_ptr,
                                               int N) {
    __shared__ int hist[128];
    __shared__ int incl[128];
    __shared__ int cur[128];
    int b = blockIdx.x;
    int t = threadIdx.x;
    int base = baseC[b];
    int cnt = baseC[b + 1] - base;
    int node0 = b << 7;

    if (t < 128) hist[t] = 0;
    __syncthreads();
    for (int i = t; i < cnt; i += 256)
        atomicAdd(&hist[part[base + i].y & 127], 1);
    __syncthreads();
    if (t < 128) incl[t] = hist[t];
    __syncthreads();
    for (int off = 1; off < 128; off <<= 1) {
        int v = 0;
        if (t < 128 && t >= off) v = incl[t - off];
        __syncthreads();
        if (t < 128) incl[t] += v;
        __syncthreads();
    }
    if (t < 128) cur[t] = incl[t] - hist[t];
    __syncthreads();
    for (int i = t; i < cnt; i += 256) {
        uint2 e = part[base + i];
        int r = atomicAdd(&cur[e.y & 127], 1);
        srcs[base + r] = (int)e.x;
    }
    int nodes = N - node0; if (nodes > 128) nodes = 128;
    if (t < nodes) row_ptr[node0 + t + 1] = base + incl[t];
    if (b == 0 && t == 0) row_ptr[0] = 0;
}

// ---------------- degree-bucket sort of dst nodes (LDS-hist) ----------------
#define NCH 8192
__global__ __launch_bounds__(256) void k_deghist(const int* __restrict__ row_ptr,
                                                 int* __restrict__ histD, int N) {
    __shared__ int h[128];
    int t = threadIdx.x;
    if (t < 128) h[t] = 0;
    __syncthreads();
    int c0 = blockIdx.x * NCH;
    int cnt = N - c0; if (cnt > NCH) cnt = NCH;
    for (int i = t; i < cnt; i += 256) {
        int deg = row_ptr[c0 + i + 1] - row_ptr[c0 + i];
        int c = deg < 127 ? deg : 127;
        atomicAdd(&h[c], 1);
    }
    __syncthreads();
    if (t < 128 && h[t]) atomicAdd(&histD[t], h[t]);
}

__global__ __launch_bounds__(256) void k_degpart(const int* __restrict__ row_ptr,
                                                 const int* __restrict__ histD,
                                                 int* __restrict__ cursor0D,
                                                 int* __restrict__ order, int N) {
    __shared__ int hist[128];
    __shared__ int gex[128];
    __shared__ int excl[128];
    __shared__ int cur[128];
    __shared__ int resB[128];
    __shared__ int stage[NCH];
    int t = threadIdx.x;
    int c0 = blockIdx.x * NCH;
    int cnt = N - c0; if (cnt > NCH) cnt = NCH;

    int g0 = 0;
    if (t < 128) { hist[t] = 0; g0 = histD[t]; gex[t] = g0; }
    __syncthreads();
    for (int i = t; i < cnt; i += 256) {
        int deg = row_ptr[c0 + i + 1] - row_ptr[c0 + i];
        int c = deg < 127 ? deg : 127;
        atomicAdd(&hist[c], 1);
    }
    __syncthreads();
    for (int off = 1; off < 128; off <<= 1) {
        int v = 0;
        if (t < 128 && t >= off) v = gex[t - off];
        __syncthreads();
        if (t < 128) gex[t] += v;
        __syncthreads();
    }
    if (t < 128) resB[t] = (gex[t] - g0) + (hist[t] ? atomicAdd(&cursor0D[t], hist[t]) : 0);
    if (t < 128) excl[t] = hist[t];
    __syncthreads();
    for (int off = 1; off < 128; off <<= 1) {
        int v = 0;
        if (t < 128 && t >= off) v = excl[t - off];
        __syncthreads();
        if (t < 128) excl[t] += v;
        __syncthreads();
    }
    if (t < 128) { excl[t] -= hist[t]; cur[t] = excl[t]; }
    __syncthreads();
    for (int i = t; i < cnt; i += 256) {
        int deg = row_ptr[c0 + i + 1] - row_ptr[c0 + i];
        int c = deg < 127 ? deg : 127;
        int p = atomicAdd(&cur[c], 1);
        stage[p] = (c << 20) | (c0 + i);   // N < 2^20
    }
    __syncthreads();
    for (int i = t; i < cnt; i += 256) {
        int v = stage[i];
        int c = v >> 20;
        order[resB[c] + (i - excl[c])] = v & 0xFFFFF;
    }
}

// ---------------- MFMA GEMM: [xl|xr][M,128each] = A[M,128] @ W[128,256] ----------------
// Proven LDS structure + T14 prefetch; XCD-paired 1D grid; F32SRC=1 stages
// layer 0 directly from x (f32) with in-register hi/lo split.
__device__ __forceinline__ void cvt8(const float4& a, const float4& b, uint4& hi, uint4& lo) {
    union US8 { unsigned short s[8]; uint4 u; } H, Lo;
    float f[8] = {a.x, a.y, a.z, a.w, b.x, b.y, b.z, b.w};
#pragma unroll
    for (int i = 0; i < 8; i++) {
        unsigned short h = f2bf(f[i]);
        H.s[i] = h;
        Lo.s[i] = f2bf(f[i] - bf2f(h));
    }
    hi = H.u; lo = Lo.u;
}

template <int F32SRC>
__global__ __launch_bounds__(256) void k_gemm(const float* __restrict__ Xf,
                                              const unsigned short* __restrict__ Ahi,
                                              const unsigned short* __restrict__ Alo,
                                              const unsigned short* __restrict__ Wth,
                                              const unsigned short* __restrict__ Wtl,
                                              _Float16* __restrict__ xl, _Float16* __restrict__ xr,
                                              int M, int L, int gX) {
    __shared__ unsigned short sA[2][128][40];
    __shared__ unsigned short sB[2][128][40];
    int b = blockIdx.x;
    int grp = b >> 4, j8 = b & 7, half = (b >> 3) & 1;
    int ry = grp * 8 + j8;
    if (ry >= gX) return;

    int t = threadIdx.x;
    int lane = t & 63;
    int l15 = lane & 15;
    int quad = lane >> 4;
    int wave = t >> 6;
    int wm = wave & 1;
    int wn = wave >> 1;
    int r0 = ry * 128;
    const unsigned short* WthL = Wth + ((size_t)L * 256 + half * 128) * 128;
    const unsigned short* WtlL = Wtl + ((size_t)L * 256 + half * 128) * 128;

    int row0 = t >> 2,       row1 = (t + 256) >> 2;
    int kq   = (t & 3) * 8;
    int gr0 = r0 + row0; gr0 = gr0 < M ? gr0 : M - 1;
    int gr1 = r0 + row1; gr1 = gr1 < M ? gr1 : M - 1;

    uint4 rAh0, rAh1, rAl0, rAl1, rBh0, rBh1, rBl0, rBl1;
    float4 f00, f01, f10, f11;

#define GLOADA(K0)                                                          \
    if (F32SRC) {                                                           \
        f00 = *(const float4*)(Xf + (size_t)gr0 * DD + (K0) + kq);          \
        f01 = *(const float4*)(Xf + (size_t)gr0 * DD + (K0) + kq + 4);      \
        f10 = *(const float4*)(Xf + (size_t)gr1 * DD + (K0) + kq);          \
        f11 = *(const float4*)(Xf + (size_t)gr1 * DD + (K0) + kq + 4);      \
    } else {                                                                \
        rAh0 = *(const uint4*)(Ahi + (size_t)gr0 * DD + (K0) + kq);         \
        rAh1 = *(const uint4*)(Ahi + (size_t)gr1 * DD + (K0) + kq);         \
        rAl0 = *(const uint4*)(Alo + (size_t)gr0 * DD + (K0) + kq);         \
        rAl1 = *(const uint4*)(Alo + (size_t)gr1 * DD + (K0) + kq);         \
    }
#define GLOADB(K0)                                                          \
    rBh0 = *(const uint4*)(WthL + (size_t)row0 * DD + (K0) + kq);           \
    rBh1 = *(const uint4*)(WthL + (size_t)row1 * DD + (K0) + kq);           \
    rBl0 = *(const uint4*)(WtlL + (size_t)row0 * DD + (K0) + kq);           \
    rBl1 = *(const uint4*)(WtlL + (size_t)row1 * DD + (K0) + kq);

    f32x4 acc[4][4] = {};
    union F8 { short8 v; uint4 u; };

    GLOADA(0);
    GLOADB(0);

#pragma unroll
    for (int kc = 0; kc < 4; kc++) {
        if (kc) __syncthreads();
        if (F32SRC) {
            cvt8(f00, f01, rAh0, rAl0);
            cvt8(f10, f11, rAh1, rAl1);
        }
        *(uint4*)&sA[0][row0][kq] = rAh0;
        *(uint4*)&sA[0][row1][kq] = rAh1;
        *(uint4*)&sA[1][row0][kq] = rAl0;
        *(uint4*)&sA[1][row1][kq] = rAl1;
        *(uint4*)&sB[0][row0][kq] = rBh0;
        *(uint4*)&sB[0][row1][kq] = rBh1;
        *(uint4*)&sB[1][row0][kq] = rBl0;
        *(uint4*)&sB[1][row1][kq] = rBl1;
        __syncthreads();
        if (kc < 3) { GLOADA((kc + 1) * 32); GLOADB((kc + 1) * 32); }  // T14

        F8 ah[4], al[4], bh[4], bl[4];
#pragma unroll
        for (int mt = 0; mt < 4; mt++) {
            ah[mt].u = *(const uint4*)&sA[0][wm * 64 + mt * 16 + l15][quad * 8];
            al[mt].u = *(const uint4*)&sA[1][wm * 64 + mt * 16 + l15][quad * 8];
        }
#pragma unroll
        for (int nt = 0; nt < 4; nt++) {
            bh[nt].u = *(const uint4*)&sB[0][wn * 64 + nt * 16 + l15][quad * 8];
            bl[nt].u = *(const uint4*)&sB[1][wn * 64 + nt * 16 + l15][quad * 8];
        }
#pragma unroll
        for (int mt = 0; mt < 4; mt++)
#pragma unroll
            for (int nt = 0; nt < 4; nt++) {
                acc[mt][nt] = __builtin_amdgcn_mfma_f32_16x16x32_bf16(ah[mt].v, bh[nt].v, acc[mt][nt], 0, 0, 0);
                acc[mt][nt] = __builtin_amdgcn_mfma_f32_16x16x32_bf16(al[mt].v, bh[nt].v, acc[mt][nt], 0, 0, 0);
                acc[mt][nt] = __builtin_amdgcn_mfma_f32_16x16x32_bf16(ah[mt].v, bl[nt].v, acc[mt][nt], 0, 0, 0);
            }
    }
#undef GLOADA
#undef GLOADB

    _Float16* C = half ? xr : xl;
#pragma unroll
    for (int mt = 0; mt < 4; mt++)
#pragma unroll
        for (int r = 0; r < 4; r++) {
            int row = r0 + wm * 64 + mt * 16 + quad * 4 + r;
            if (row < M) {
#pragma unroll
                for (int nt = 0; nt < 4; nt++)
                    C[(size_t)row * DD + wn * 64 + nt * 16 + l15] = (_Float16)acc[mt][nt][r];
            }
        }
}

// ---------------- fused per-dst attention + aggregate ----------------
// NOTE (r5/r6): pinned at random-gather cache bandwidth (~3.6 TB/s TCC);
// multiple structural variants all land at ~70us with FETCH ~200MB. Frozen.
__global__ __launch_bounds__(256) void k_attn(const _Float16* __restrict__ xl,
                                              const _Float16* __restrict__ xr,
                                              const int* __restrict__ row_ptr,
                                              const int* __restrict__ srcs,
                                              const int* __restrict__ order,
                                              const float* __restrict__ att,
                                              const float* __restrict__ bias,
                                              float* __restrict__ outF,
                                              unsigned short* __restrict__ outHi,
                                              unsigned short* __restrict__ outLo,
                                              int n, int mode) {
    int wid = (blockIdx.x * blockDim.x + threadIdx.x) >> 6;
    int l = threadIdx.x & 63;
    int l15 = l & 15;
    int g = l >> 4;
    int idx = wid * 4 + g;
    bool act = idx < n;
    int d = act ? order[idx] : 0;

    union Q { uint4 q; h2v h[4]; };
    const float LOG2E = 1.44269504088896f;

    h2v at[4], xrh[4];
    {
        float4 a0 = *(const float4*)(att + l15 * 8);
        float4 a1 = *(const float4*)(att + l15 * 8 + 4);
        at[0] = h2v{(_Float16)(a0.x * LOG2E), (_Float16)(a0.y * LOG2E)};
        at[1] = h2v{(_Float16)(a0.z * LOG2E), (_Float16)(a0.w * LOG2E)};
        at[2] = h2v{(_Float16)(a1.x * LOG2E), (_Float16)(a1.y * LOG2E)};
        at[3] = h2v{(_Float16)(a1.z * LOG2E), (_Float16)(a1.w * LOG2E)};
        Q hr; hr.q = *(const uint4*)(xr + (size_t)d * DD + l15 * 8);
#pragma unroll
        for (int j = 0; j < 4; j++) xrh[j] = hr.h[j];
    }
    const _Float16 cneg = (_Float16)NEG;

    int beg = act ? row_ptr[d] : 0;
    int end = act ? row_ptr[d + 1] : 0;
    int cnt = end - beg;

    int mc = cnt;
    mc = max(mc, __shfl_xor(mc, 16, 64));
    mc = max(mc, __shfl_xor(mc, 32, 64));
    int iters = (mc + 3) >> 2;

    float lse = 0.f;
    float av[8] = {};

    int i0 = beg, i1 = beg + 1, i2 = beg + 2, i3 = beg + 3;
    bool v0 = i0 < end, v1 = i1 < end, v2 = i2 < end, v3 = i3 < end;
    int s0 = v0 ? srcs[i0] : 0;
    int s1 = v1 ? srcs[i1] : 0;
    int s2 = v2 ? srcs[i2] : 0;
    int s3 = v3 ? srcs[i3] : 0;

    const _Float16* xlp = xl + l15 * 8;

    for (int it = 0; it < iters; ++it) {
        Q h0, h1, h2, h3;
        h0.q = *(const uint4*)(xlp + (size_t)s0 * DD);
        h1.q = *(const uint4*)(xlp + (size_t)s1 * DD);
        h2.q = *(const uint4*)(xlp + (size_t)s2 * DD);
        h3.q = *(const uint4*)(xlp + (size_t)s3 * DD);
        int n0 = i0 + 4, n1 = i1 + 4, n2 = i2 + 4, n3 = i3 + 4;
        bool nv0 = n0 < end, nv1 = n1 < end, nv2 = n2 < end, nv3 = n3 < end;
        int t0 = nv0 ? srcs[n0] : 0;
        int t1 = nv1 ? srcs[n1] : 0;
        int t2 = nv2 ? srcs[n2] : 0;
        int t3 = nv3 ? srcs[n3] : 0;

        float p0 = 0.f, p1 = 0.f, p2 = 0.f, p3 = 0.f;
#pragma unroll
        for (int j = 0; j < 4; j++) {
            h2v z0 = h0.h[j] + xrh[j];
            h2v zl0 = __builtin_elementwise_max(z0, z0 * cneg);
            p0 = __builtin_amdgcn_fdot2(zl0, at[j], p0, false);
            h2v z1 = h1.h[j] + xrh[j];
            h2v zl1 = __builtin_elementwise_max(z1, z1 * cneg);
            p1 = __builtin_amdgcn_fdot2(zl1, at[j], p1, false);
            h2v z2 = h2.h[j] + xrh[j];
            h2v zl2 = __builtin_elementwise_max(z2, z2 * cneg);
            p2 = __builtin_amdgcn_fdot2(zl2, at[j], p2, false);
            h2v z3 = h3.h[j] + xrh[j];
            h2v zl3 = __builtin_elementwise_max(z3, z3 * cneg);
            p3 = __builtin_amdgcn_fdot2(zl3, at[j], p3, false);
        }
        p0 += __shfl_xor(p0, 1, 64);  p1 += __shfl_xor(p1, 1, 64);
        p2 += __shfl_xor(p2, 1, 64);  p3 += __shfl_xor(p3, 1, 64);
        p0 += __shfl_xor(p0, 2, 64);  p1 += __shfl_xor(p1, 2, 64);
        p2 += __shfl_xor(p2, 2, 64);  p3 += __shfl_xor(p3, 2, 64);
        p0 += __shfl_xor(p0, 4, 64);  p1 += __shfl_xor(p1, 4, 64);
        p2 += __shfl_xor(p2, 4, 64);  p3 += __shfl_xor(p3, 4, 64);
        p0 += __shfl_xor(p0, 8, 64);  p1 += __shfl_xor(p1, 8, 64);
        p2 += __shfl_xor(p2, 8, 64);  p3 += __shfl_xor(p3, 8, 64);
        p0 = fminf(fmaxf(p0, -86.f), 86.f);
        p1 = fminf(fmaxf(p1, -86.f), 86.f);
        p2 = fminf(fmaxf(p2, -86.f), 86.f);
        p3 = fminf(fmaxf(p3, -86.f), 86.f);
        float w0 = v0 ? EXP2F(p0) : 0.f;
        float w1 = v1 ? EXP2F(p1) : 0.f;
        float w2 = v2 ? EXP2F(p2) : 0.f;
        float w3 = v3 ? EXP2F(p3) : 0.f;
        lse += (w0 + w1) + (w2 + w3);
#pragma unroll
        for (int j = 0; j < 4; j++) {
            av[2 * j]     += (float)h0.h[j][0] * w0;
            av[2 * j + 1] += (float)h0.h[j][1] * w0;
            av[2 * j]     += (float)h1.h[j][0] * w1;
            av[2 * j + 1] += (float)h1.h[j][1] * w1;
            av[2 * j]     += (float)h2.h[j][0] * w2;
            av[2 * j + 1] += (float)h2.h[j][1] * w2;
            av[2 * j]     += (float)h3.h[j][0] * w3;
            av[2 * j + 1] += (float)h3.h[j][1] * w3;
        }
        i0 = n0; i1 = n1; i2 = n2; i3 = n3;
        v0 = nv0; v1 = nv1; v2 = nv2; v3 = nv3;
        s0 = t0; s1 = t1; s2 = t2; s3 = t3;
    }

    if (act) {
        float inv = (cnt > 0) ? 1.0f / lse : 0.f;
        float o[8];
        float4 b0 = *(const float4*)(bias + l15 * 8);
        float4 b1 = *(const float4*)(bias + l15 * 8 + 4);
        float bv[8] = {b0.x, b0.y, b0.z, b0.w, b1.x, b1.y, b1.z, b1.w};
#pragma unroll
        for (int j = 0; j < 8; j++) o[j] = av[j] * inv + bv[j];
        if (mode) {
            union U8 { unsigned short s[8]; uint4 q; };
            U8 hh, ll;
#pragma unroll
            for (int j = 0; j < 8; j++) {
                float v = fmaxf(o[j], 0.f);
                hh.s[j] = f2bf(v);
                ll.s[j] = f2bf(v - bf2f(hh.s[j]));
            }
            *(uint4*)(outHi + (size_t)d * DD + l15 * 8) = hh.q;
            *(uint4*)(outLo + (size_t)d * DD + l15 * 8) = ll.q;
        } else {
            float4 o0 = {o[0], o[1], o[2], o[3]};
            float4 o1 = {o[4], o[5], o[6], o[7]};
            float* op = outF + (size_t)d * DD + l15 * 8;
            *(float4*)op = o0;
            *(float4*)(op + 4) = o1;
        }
    }
}

// ---------------- launch ----------------
extern "C" void kernel_launch(void* const* d_in, const int* in_sizes, int n_in,
                              void* d_out, int out_size, void* d_ws, size_t ws_size,
                              hipStream_t stream) {
    const float* x    = (const float*)d_in[0];
    const float* Wl   = (const float*)d_in[1];
    const float* Wr   = (const float*)d_in[2];
    const float* att  = (const float*)d_in[3];
    const float* bias = (const float*)d_in[4];
    const int*   ei   = (const int*)d_in[5];

    int N = in_sizes[0] / DD;
    int E = in_sizes[5] / 2;
    const int* srcI = ei;
    const int* dstI = ei + E;
    float* out = (float*)d_out;
    int CB = (N + 127) >> 7;

    char* ws = (char*)d_ws;
    size_t off = 0;
    auto alloc = [&](size_t bytes) -> void* {
        void* p = ws + off;
        off += (bytes + 255) & ~(size_t)255;
        return p;
    };
    _Float16*       xl   = (_Float16*)alloc((size_t)N * DD * 2);
    _Float16*       xr   = (_Float16*)alloc((size_t)N * DD * 2);
    unsigned short* Ahi  = (unsigned short*)alloc((size_t)N * DD * 2);
    unsigned short* Alo  = (unsigned short*)alloc((size_t)N * DD * 2);
    unsigned short* Wth  = (unsigned short*)alloc((size_t)3 * 256 * 128 * 2);
    unsigned short* Wtl  = (unsigned short*)alloc((size_t)3 * 256 * 128 * 2);
    uint2* part    = (uint2*)alloc((size_t)E * 8);
    int*   srcs    = (int*)alloc((size_t)E * 4);
    int*   row_ptr = (int*)alloc((size_t)(N + 1) * 4);
    int*   order   = (int*)alloc((size_t)N * 4);
    int*   baseC   = (int*)alloc((size_t)(CB + 1) * 4);
    // zero-block: histC[CB] | cursor0C[CB] | histD[128] | cursor0D[128]
    int*   z       = (int*)alloc((size_t)(2 * CB + 256) * 4);
    int*   histC    = z;
    int*   cursor0C = z + CB;
    int*   histD    = z + 2 * CB;
    int*   cursor0D = z + 2 * CB + 128;

    const int tb = 256;
    (void)hipMemsetAsync(z, 0, (size_t)(2 * CB + 256) * 4, stream);
    k_histC<<<640, 256, 0, stream>>>(dstI, histC, E, CB, Wl, Wr, Wth, Wtl);
    k_part3<<<(E + CHUNK - 1) / CHUNK, 256, 0, stream>>>(srcI, dstI, histC, cursor0C,
                                                         baseC, part, E, CB);
    k_part4<<<CB, 256, 0, stream>>>(part, baseC, srcs, row_ptr, N);
    int gD = (N + NCH - 1) / NCH;
    k_deghist<<<gD, 256, 0, stream>>>(row_ptr, histD, N);
    k_degpart<<<gD, 256, 0, stream>>>(row_ptr, histD, cursor0D, order, N);

    int gX = (N + 127) / 128;
    int NB = 16 * ((gX + 7) / 8);   // XCD-paired 1D grid (j and j+8 share an XCD)
    for (int L = 0; L < 3; ++L) {
        if (L == 0)
            k_gemm<1><<<NB, 256, 0, stream>>>(x, Ahi, Alo, Wth, Wtl, xl, xr, N, L, gX);
        else
            k_gemm<0><<<NB, 256, 0, stream>>>(x, Ahi, Alo, Wth, Wtl, xl, xr, N, L, gX);
        k_attn<<<((size_t)N * 16 + tb - 1) / tb, tb, 0, stream>>>(
            xl, xr, row_ptr, srcs, order, att + (size_t)L * DD, bias + (size_t)L * DD,
            out, Ahi, Alo, N, (L < 2) ? 1 : 0);
    }
}

// Round 10
// 473.440 us; speedup vs baseline: 1.2750x; 1.0310x over previous
//
#include <hip/hip_runtime.h>
#include <math.h>

#define DD 128
#define NEG 0.2f

typedef short short8 __attribute__((ext_vector_type(8)));
typedef float f32x4 __attribute__((ext_vector_type(4)));
typedef float f32x2 __attribute__((ext_vector_type(2)));
typedef _Float16 h2v __attribute__((ext_vector_type(2)));

__device__ __forceinline__ unsigned short f2bf(float f) {
    unsigned u = __float_as_uint(f);
    return (unsigned short)((u + 0x7fffu + ((u >> 16) & 1u)) >> 16);
}
__device__ __forceinline__ float bf2f(unsigned short h) {
    return __uint_as_float(((unsigned)h) << 16);
}

#if __has_builtin(__builtin_amdgcn_exp2f)
#define EXP2F(x) __builtin_amdgcn_exp2f(x)
#else
#define EXP2F(x) exp2f(x)
#endif

// ======================= CSR build =======================
// HW lessons: (r8) scattered device-scope atomics are memory-side 64B RMWs —
// LDS aggregation mandatory. (r9) scattered small stores suffer cross-XCD
// partial-line write amplification — LDS-staged contiguous write-out is
// load-bearing. This round: r7's staged two-level partition, but with
// (a) part[] packed to 4B (src | (dst&127)<<25; valid for N < 2^25),
// (b) CHUNK 4096 + hoisted histC scan -> part3 LDS 45KB, 391 blocks,
// (c) part4 srcS 4096 -> 17.5KB LDS, 9 blocks/CU.

// exclusive scan in-place over sh[0..1024) (must be zero-padded), 256 threads.
__device__ void excl_scan_1024(int* sh, int* aux) {
    __syncthreads();
    int t = threadIdx.x;
    int base = t * 4;
    int a0 = sh[base], a1 = sh[base + 1], a2 = sh[base + 2], a3 = sh[base + 3];
    int s = a0 + a1 + a2 + a3;
    aux[t] = s;
    __syncthreads();
    for (int off = 1; off < 256; off <<= 1) {
        int v = (t >= off) ? aux[t - off] : 0;
        __syncthreads();
        aux[t] += v;
        __syncthreads();
    }
    int excl = aux[t] - s;
    sh[base] = excl;
    sh[base + 1] = excl + a0;
    sh[base + 2] = excl + a0 + a1;
    sh[base + 3] = excl + a0 + a1 + a2;
    __syncthreads();
}

// ---------------- fused: global dst-chunk histogram + weight cast ----------------
__global__ __launch_bounds__(256) void k_histC(const int* __restrict__ dst,
                                               int* __restrict__ histC, int E, int CB,
                                               const float* __restrict__ Wl,
                                               const float* __restrict__ Wr,
                                               unsigned short* __restrict__ Wth,
                                               unsigned short* __restrict__ Wtl) {
    __shared__ int h[1024];
    int t = threadIdx.x;
    if (blockIdx.x >= 256) {
        int idx = (blockIdx.x - 256) * 256 + t;
        if (idx < 3 * 256 * 128) {
            int L = idx >> 15;
            int rem = idx & 32767;
            int nn = rem >> 7;
            int k = rem & 127;
            float v = (nn < 128) ? Wl[L * 16384 + k * 128 + nn]
                                 : Wr[L * 16384 + k * 128 + (nn - 128)];
            unsigned short hh = f2bf(v);
            Wth[idx] = hh;
            Wtl[idx] = f2bf(v - bf2f(hh));
        }
        return;
    }
    for (int j = t; j < 1024; j += 256) h[j] = 0;
    __syncthreads();
    int stride = 256 * 256;
    for (int i = blockIdx.x * 256 + t; i < E; i += stride)
        atomicAdd(&h[dst[i] >> 7], 1);
    __syncthreads();
    for (int j = t; j < CB; j += 256)
        if (h[j]) atomicAdd(&histC[j], h[j]);
}

// ---------------- global scan of histC -> baseC (1 block) ----------------
__global__ __launch_bounds__(256) void k_scanC2(const int* __restrict__ histC,
                                                int* __restrict__ baseC, int CB) {
    __shared__ int sh[1024];
    __shared__ int aux[256];
    int t = threadIdx.x;
    for (int j = t; j < 1024; j += 256) sh[j] = (j < CB) ? histC[j] : 0;
    excl_scan_1024(sh, aux);
    for (int j = t; j <= CB; j += 256) baseC[j] = sh[j];
}

// ---------------- CSR partition pass 1 (staged, packed output) ----------------
#define CHUNK 4096
__global__ __launch_bounds__(256) void k_part3(const int* __restrict__ srcI,
                                               const int* __restrict__ dstI,
                                               const int* __restrict__ baseC,
                                               int* __restrict__ cursor0C,
                                               unsigned* __restrict__ part,
                                               int E, int CB) {
    __shared__ int sh[1024];
    __shared__ int aux[256];
    __shared__ int resBase[1024];
    __shared__ int cur[1024];
    __shared__ uint2 stage[CHUNK];
    int t = threadIdx.x;
    int c0 = blockIdx.x * CHUNK;
    int cnt = E - c0; if (cnt > CHUNK) cnt = CHUNK;

    for (int j = t; j < 1024; j += 256) sh[j] = 0;
    __syncthreads();
    for (int i = t; i < cnt; i += 256)
        atomicAdd(&sh[dstI[c0 + i] >> 7], 1);
    __syncthreads();
    for (int j = t; j < CB; j += 256) {
        int c = sh[j];
        resBase[j] = baseC[j] + (c ? atomicAdd(&cursor0C[j], c) : 0);
    }
    excl_scan_1024(sh, aux);            // leading barrier covers resBase reads
    for (int j = t; j < 1024; j += 256) cur[j] = sh[j];
    __syncthreads();
    for (int i = t; i < cnt; i += 256) {
        unsigned s = (unsigned)srcI[c0 + i];
        unsigned d = (unsigned)dstI[c0 + i];
        int b = (int)(d >> 7);
        int pos = atomicAdd(&cur[b], 1);
        stage[pos].x = s;
        stage[pos].y = d;
    }
    __syncthreads();
    // contiguous-per-bucket write-out (full-line bursts), packed to 4B
    for (int i = t; i < cnt; i += 256) {
        uint2 v = stage[i];
        int b = (int)(v.y >> 7);
        part[resBase[b] + (i - sh[b])] = v.x | ((v.y & 127u) << 25);
    }
}

// ---------------- CSR partition pass 2 (staged, packed input) ----------------
__global__ __launch_bounds__(256) void k_part4(const unsigned* __restrict__ part,
                                               const int* __restrict__ baseC,
                                               int* __restrict__ srcs,
                                               int* __restrict__ row_ptr,
                                               int N) {
    __shared__ int hist[128];
    __shared__ int incl[128];
    __shared__ int cur[128];
    __shared__ int srcS[4096];
    int b = blockIdx.x;
    int t = threadIdx.x;
    int base = baseC[b];
    int cnt = baseC[b + 1] - base;
    int node0 = b << 7;

    if (t < 128) hist[t] = 0;
    __syncthreads();
    for (int i = t; i < cnt; i += 256)
        atomicAdd(&hist[part[base + i] >> 25], 1);
    __syncthreads();
    if (t < 128) incl[t] = hist[t];
    __syncthreads();
    for (int off = 1; off < 128; off <<= 1) {
        int v = 0;
        if (t < 128 && t >= off) v = incl[t - off];
        __syncthreads();
        if (t < 128) incl[t] += v;
        __syncthreads();
    }
    if (t < 128) cur[t] = incl[t] - hist[t];
    __syncthreads();
    for (int i = t; i < cnt; i += 256) {
        unsigned v = part[base + i];
        int r = atomicAdd(&cur[v >> 25], 1);
        if (r < 4096) srcS[r] = (int)(v & 0x1FFFFFFu);
    }
    __syncthreads();
    for (int i = t; i < cnt; i += 256)
        srcs[base + i] = srcS[i];
    int nodes = N - node0; if (nodes > 128) nodes = 128;
    if (t < nodes) row_ptr[node0 + t + 1] = base + incl[t];
    if (b == 0 && t == 0) row_ptr[0] = 0;
}

// ---------------- degree-bucket sort of dst nodes (LDS-hist) ----------------
#define NCH 8192
__global__ __launch_bounds__(256) void k_deghist(const int* __restrict__ row_ptr,
                                                 int* __restrict__ histD, int N) {
    __shared__ int h[128];
    int t = threadIdx.x;
    if (t < 128) h[t] = 0;
    __syncthreads();
    int c0 = blockIdx.x * NCH;
    int cnt = N - c0; if (cnt > NCH) cnt = NCH;
    for (int i = t; i < cnt; i += 256) {
        int deg = row_ptr[c0 + i + 1] - row_ptr[c0 + i];
        int c = deg < 127 ? deg : 127;
        atomicAdd(&h[c], 1);
    }
    __syncthreads();
    if (t < 128 && h[t]) atomicAdd(&histD[t], h[t]);
}

__global__ __launch_bounds__(256) void k_degpart(const int* __restrict__ row_ptr,
                                                 const int* __restrict__ histD,
                                                 int* __restrict__ cursor0D,
                                                 int* __restrict__ order, int N) {
    __shared__ int hist[128];
    __shared__ int gex[128];
    __shared__ int excl[128];
    __shared__ int cur[128];
    __shared__ int resB[128];
    __shared__ int stage[NCH];
    int t = threadIdx.x;
    int c0 = blockIdx.x * NCH;
    int cnt = N - c0; if (cnt > NCH) cnt = NCH;

    int g0 = 0;
    if (t < 128) { hist[t] = 0; g0 = histD[t]; gex[t] = g0; }
    __syncthreads();
    for (int i = t; i < cnt; i += 256) {
        int deg = row_ptr[c0 + i + 1] - row_ptr[c0 + i];
        int c = deg < 127 ? deg : 127;
        atomicAdd(&hist[c], 1);
    }
    __syncthreads();
    for (int off = 1; off < 128; off <<= 1) {
        int v = 0;
        if (t < 128 && t >= off) v = gex[t - off];
        __syncthreads();
        if (t < 128) gex[t] += v;
        __syncthreads();
    }
    if (t < 128) resB[t] = (gex[t] - g0) + (hist[t] ? atomicAdd(&cursor0D[t], hist[t]) : 0);
    if (t < 128) excl[t] = hist[t];
    __syncthreads();
    for (int off = 1; off < 128; off <<= 1) {
        int v = 0;
        if (t < 128 && t >= off) v = excl[t - off];
        __syncthreads();
        if (t < 128) excl[t] += v;
        __syncthreads();
    }
    if (t < 128) { excl[t] -= hist[t]; cur[t] = excl[t]; }
    __syncthreads();
    for (int i = t; i < cnt; i += 256) {
        int deg = row_ptr[c0 + i + 1] - row_ptr[c0 + i];
        int c = deg < 127 ? deg : 127;
        int p = atomicAdd(&cur[c], 1);
        stage[p] = (c << 20) | (c0 + i);   // N < 2^20
    }
    __syncthreads();
    for (int i = t; i < cnt; i += 256) {
        int v = stage[i];
        int c = v >> 20;
        order[resB[c] + (i - excl[c])] = v & 0xFFFFF;
    }
}

// ---------------- MFMA GEMM: [xl|xr][M,128each] = A[M,128] @ W[128,256] ----------------
// Proven LDS structure + T14 prefetch; XCD-paired 1D grid; F32SRC=1 stages
// layer 0 directly from x (f32) with in-register hi/lo split.
__device__ __forceinline__ void cvt8(const float4& a, const float4& b, uint4& hi, uint4& lo) {
    union US8 { unsigned short s[8]; uint4 u; } H, Lo;
    float f[8] = {a.x, a.y, a.z, a.w, b.x, b.y, b.z, b.w};
#pragma unroll
    for (int i = 0; i < 8; i++) {
        unsigned short h = f2bf(f[i]);
        H.s[i] = h;
        Lo.s[i] = f2bf(f[i] - bf2f(h));
    }
    hi = H.u; lo = Lo.u;
}

template <int F32SRC>
__global__ __launch_bounds__(256) void k_gemm(const float* __restrict__ Xf,
                                              const unsigned short* __restrict__ Ahi,
                                              const unsigned short* __restrict__ Alo,
                                              const unsigned short* __restrict__ Wth,
                                              const unsigned short* __restrict__ Wtl,
                                              _Float16* __restrict__ xl, _Float16* __restrict__ xr,
                                              int M, int L, int gX) {
    __shared__ unsigned short sA[2][128][40];
    __shared__ unsigned short sB[2][128][40];
    int b = blockIdx.x;
    int grp = b >> 4, j8 = b & 7, half = (b >> 3) & 1;
    int ry = grp * 8 + j8;
    if (ry >= gX) return;

    int t = threadIdx.x;
    int lane = t & 63;
    int l15 = lane & 15;
    int quad = lane >> 4;
    int wave = t >> 6;
    int wm = wave & 1;
    int wn = wave >> 1;
    int r0 = ry * 128;
    const unsigned short* WthL = Wth + ((size_t)L * 256 + half * 128) * 128;
    const unsigned short* WtlL = Wtl + ((size_t)L * 256 + half * 128) * 128;

    int row0 = t >> 2,       row1 = (t + 256) >> 2;
    int kq   = (t & 3) * 8;
    int gr0 = r0 + row0; gr0 = gr0 < M ? gr0 : M - 1;
    int gr1 = r0 + row1; gr1 = gr1 < M ? gr1 : M - 1;

    uint4 rAh0, rAh1, rAl0, rAl1, rBh0, rBh1, rBl0, rBl1;
    float4 f00, f01, f10, f11;

#define GLOADA(K0)                                                          \
    if (F32SRC) {                                                           \
        f00 = *(const float4*)(Xf + (size_t)gr0 * DD + (K0) + kq);          \
        f01 = *(const float4*)(Xf + (size_t)gr0 * DD + (K0) + kq + 4);      \
        f10 = *(const float4*)(Xf + (size_t)gr1 * DD + (K0) + kq);          \
        f11 = *(const float4*)(Xf + (size_t)gr1 * DD + (K0) + kq + 4);      \
    } else {                                                                \
        rAh0 = *(const uint4*)(Ahi + (size_t)gr0 * DD + (K0) + kq);         \
        rAh1 = *(const uint4*)(Ahi + (size_t)gr1 * DD + (K0) + kq);         \
        rAl0 = *(const uint4*)(Alo + (size_t)gr0 * DD + (K0) + kq);         \
        rAl1 = *(const uint4*)(Alo + (size_t)gr1 * DD + (K0) + kq);         \
    }
#define GLOADB(K0)                                                          \
    rBh0 = *(const uint4*)(WthL + (size_t)row0 * DD + (K0) + kq);           \
    rBh1 = *(const uint4*)(WthL + (size_t)row1 * DD + (K0) + kq);           \
    rBl0 = *(const uint4*)(WtlL + (size_t)row0 * DD + (K0) + kq);           \
    rBl1 = *(const uint4*)(WtlL + (size_t)row1 * DD + (K0) + kq);

    f32x4 acc[4][4] = {};
    union F8 { short8 v; uint4 u; };

    GLOADA(0);
    GLOADB(0);

#pragma unroll
    for (int kc = 0; kc < 4; kc++) {
        if (kc) __syncthreads();
        if (F32SRC) {
            cvt8(f00, f01, rAh0, rAl0);
            cvt8(f10, f11, rAh1, rAl1);
        }
        *(uint4*)&sA[0][row0][kq] = rAh0;
        *(uint4*)&sA[0][row1][kq] = rAh1;
        *(uint4*)&sA[1][row0][kq] = rAl0;
        *(uint4*)&sA[1][row1][kq] = rAl1;
        *(uint4*)&sB[0][row0][kq] = rBh0;
        *(uint4*)&sB[0][row1][kq] = rBh1;
        *(uint4*)&sB[1][row0][kq] = rBl0;
        *(uint4*)&sB[1][row1][kq] = rBl1;
        __syncthreads();
        if (kc < 3) { GLOADA((kc + 1) * 32); GLOADB((kc + 1) * 32); }  // T14

        F8 ah[4], al[4], bh[4], bl[4];
#pragma unroll
        for (int mt = 0; mt < 4; mt++) {
            ah[mt].u = *(const uint4*)&sA[0][wm * 64 + mt * 16 + l15][quad * 8];
            al[mt].u = *(const uint4*)&sA[1][wm * 64 + mt * 16 + l15][quad * 8];
        }
#pragma unroll
        for (int nt = 0; nt < 4; nt++) {
            bh[nt].u = *(const uint4*)&sB[0][wn * 64 + nt * 16 + l15][quad * 8];
            bl[nt].u = *(const uint4*)&sB[1][wn * 64 + nt * 16 + l15][quad * 8];
        }
#pragma unroll
        for (int mt = 0; mt < 4; mt++)
#pragma unroll
            for (int nt = 0; nt < 4; nt++) {
                acc[mt][nt] = __builtin_amdgcn_mfma_f32_16x16x32_bf16(ah[mt].v, bh[nt].v, acc[mt][nt], 0, 0, 0);
                acc[mt][nt] = __builtin_amdgcn_mfma_f32_16x16x32_bf16(al[mt].v, bh[nt].v, acc[mt][nt], 0, 0, 0);
                acc[mt][nt] = __builtin_amdgcn_mfma_f32_16x16x32_bf16(ah[mt].v, bl[nt].v, acc[mt][nt], 0, 0, 0);
            }
    }
#undef GLOADA
#undef GLOADB

    _Float16* C = half ? xr : xl;
#pragma unroll
    for (int mt = 0; mt < 4; mt++)
#pragma unroll
        for (int r = 0; r < 4; r++) {
            int row = r0 + wm * 64 + mt * 16 + quad * 4 + r;
            if (row < M) {
#pragma unroll
                for (int nt = 0; nt < 4; nt++)
                    C[(size_t)row * DD + wn * 64 + nt * 16 + l15] = (_Float16)acc[mt][nt][r];
            }
        }
}

// ---------------- fused per-dst attention + aggregate ----------------
// NOTE (r5/r6): pinned at random-gather cache bandwidth (~3.6 TB/s TCC);
// multiple structural variants all land at ~70us with FETCH ~200MB. Frozen.
__global__ __launch_bounds__(256) void k_attn(const _Float16* __restrict__ xl,
                                              const _Float16* __restrict__ xr,
                                              const int* __restrict__ row_ptr,
                                              const int* __restrict__ srcs,
                                              const int* __restrict__ order,
                                              const float* __restrict__ att,
                                              const float* __restrict__ bias,
                                              float* __restrict__ outF,
                                              unsigned short* __restrict__ outHi,
                                              unsigned short* __restrict__ outLo,
                                              int n, int mode) {
    int wid = (blockIdx.x * blockDim.x + threadIdx.x) >> 6;
    int l = threadIdx.x & 63;
    int l15 = l & 15;
    int g = l >> 4;
    int idx = wid * 4 + g;
    bool act = idx < n;
    int d = act ? order[idx] : 0;

    union Q { uint4 q; h2v h[4]; };
    const float LOG2E = 1.44269504088896f;

    h2v at[4], xrh[4];
    {
        float4 a0 = *(const float4*)(att + l15 * 8);
        float4 a1 = *(const float4*)(att + l15 * 8 + 4);
        at[0] = h2v{(_Float16)(a0.x * LOG2E), (_Float16)(a0.y * LOG2E)};
        at[1] = h2v{(_Float16)(a0.z * LOG2E), (_Float16)(a0.w * LOG2E)};
        at[2] = h2v{(_Float16)(a1.x * LOG2E), (_Float16)(a1.y * LOG2E)};
        at[3] = h2v{(_Float16)(a1.z * LOG2E), (_Float16)(a1.w * LOG2E)};
        Q hr; hr.q = *(const uint4*)(xr + (size_t)d * DD + l15 * 8);
#pragma unroll
        for (int j = 0; j < 4; j++) xrh[j] = hr.h[j];
    }
    const _Float16 cneg = (_Float16)NEG;

    int beg = act ? row_ptr[d] : 0;
    int end = act ? row_ptr[d + 1] : 0;
    int cnt = end - beg;

    int mc = cnt;
    mc = max(mc, __shfl_xor(mc, 16, 64));
    mc = max(mc, __shfl_xor(mc, 32, 64));
    int iters = (mc + 3) >> 2;

    float lse = 0.f;
    float av[8] = {};

    int i0 = beg, i1 = beg + 1, i2 = beg + 2, i3 = beg + 3;
    bool v0 = i0 < end, v1 = i1 < end, v2 = i2 < end, v3 = i3 < end;
    int s0 = v0 ? srcs[i0] : 0;
    int s1 = v1 ? srcs[i1] : 0;
    int s2 = v2 ? srcs[i2] : 0;
    int s3 = v3 ? srcs[i3] : 0;

    const _Float16* xlp = xl + l15 * 8;

    for (int it = 0; it < iters; ++it) {
        Q h0, h1, h2, h3;
        h0.q = *(const uint4*)(xlp + (size_t)s0 * DD);
        h1.q = *(const uint4*)(xlp + (size_t)s1 * DD);
        h2.q = *(const uint4*)(xlp + (size_t)s2 * DD);
        h3.q = *(const uint4*)(xlp + (size_t)s3 * DD);
        int n0 = i0 + 4, n1 = i1 + 4, n2 = i2 + 4, n3 = i3 + 4;
        bool nv0 = n0 < end, nv1 = n1 < end, nv2 = n2 < end, nv3 = n3 < end;
        int t0 = nv0 ? srcs[n0] : 0;
        int t1 = nv1 ? srcs[n1] : 0;
        int t2 = nv2 ? srcs[n2] : 0;
        int t3 = nv3 ? srcs[n3] : 0;

        float p0 = 0.f, p1 = 0.f, p2 = 0.f, p3 = 0.f;
#pragma unroll
        for (int j = 0; j < 4; j++) {
            h2v z0 = h0.h[j] + xrh[j];
            h2v zl0 = __builtin_elementwise_max(z0, z0 * cneg);
            p0 = __builtin_amdgcn_fdot2(zl0, at[j], p0, false);
            h2v z1 = h1.h[j] + xrh[j];
            h2v zl1 = __builtin_elementwise_max(z1, z1 * cneg);
            p1 = __builtin_amdgcn_fdot2(zl1, at[j], p1, false);
            h2v z2 = h2.h[j] + xrh[j];
            h2v zl2 = __builtin_elementwise_max(z2, z2 * cneg);
            p2 = __builtin_amdgcn_fdot2(zl2, at[j], p2, false);
            h2v z3 = h3.h[j] + xrh[j];
            h2v zl3 = __builtin_elementwise_max(z3, z3 * cneg);
            p3 = __builtin_amdgcn_fdot2(zl3, at[j], p3, false);
        }
        p0 += __shfl_xor(p0, 1, 64);  p1 += __shfl_xor(p1, 1, 64);
        p2 += __shfl_xor(p2, 1, 64);  p3 += __shfl_xor(p3, 1, 64);
        p0 += __shfl_xor(p0, 2, 64);  p1 += __shfl_xor(p1, 2, 64);
        p2 += __shfl_xor(p2, 2, 64);  p3 += __shfl_xor(p3, 2, 64);
        p0 += __shfl_xor(p0, 4, 64);  p1 += __shfl_xor(p1, 4, 64);
        p2 += __shfl_xor(p2, 4, 64);  p3 += __shfl_xor(p3, 4, 64);
        p0 += __shfl_xor(p0, 8, 64);  p1 += __shfl_xor(p1, 8, 64);
        p2 += __shfl_xor(p2, 8, 64);  p3 += __shfl_xor(p3, 8, 64);
        p0 = fminf(fmaxf(p0, -86.f), 86.f);
        p1 = fminf(fmaxf(p1, -86.f), 86.f);
        p2 = fminf(fmaxf(p2, -86.f), 86.f);
        p3 = fminf(fmaxf(p3, -86.f), 86.f);
        float w0 = v0 ? EXP2F(p0) : 0.f;
        float w1 = v1 ? EXP2F(p1) : 0.f;
        float w2 = v2 ? EXP2F(p2) : 0.f;
        float w3 = v3 ? EXP2F(p3) : 0.f;
        lse += (w0 + w1) + (w2 + w3);
#pragma unroll
        for (int j = 0; j < 4; j++) {
            av[2 * j]     += (float)h0.h[j][0] * w0;
            av[2 * j + 1] += (float)h0.h[j][1] * w0;
            av[2 * j]     += (float)h1.h[j][0] * w1;
            av[2 * j + 1] += (float)h1.h[j][1] * w1;
            av[2 * j]     += (float)h2.h[j][0] * w2;
            av[2 * j + 1] += (float)h2.h[j][1] * w2;
            av[2 * j]     += (float)h3.h[j][0] * w3;
            av[2 * j + 1] += (float)h3.h[j][1] * w3;
        }
        i0 = n0; i1 = n1; i2 = n2; i3 = n3;
        v0 = nv0; v1 = nv1; v2 = nv2; v3 = nv3;
        s0 = t0; s1 = t1; s2 = t2; s3 = t3;
    }

    if (act) {
        float inv = (cnt > 0) ? 1.0f / lse : 0.f;
        float o[8];
        float4 b0 = *(const float4*)(bias + l15 * 8);
        float4 b1 = *(const float4*)(bias + l15 * 8 + 4);
        float bv[8] = {b0.x, b0.y, b0.z, b0.w, b1.x, b1.y, b1.z, b1.w};
#pragma unroll
        for (int j = 0; j < 8; j++) o[j] = av[j] * inv + bv[j];
        if (mode) {
            union U8 { unsigned short s[8]; uint4 q; };
            U8 hh, ll;
#pragma unroll
            for (int j = 0; j < 8; j++) {
                float v = fmaxf(o[j], 0.f);
                hh.s[j] = f2bf(v);
                ll.s[j] = f2bf(v - bf2f(hh.s[j]));
            }
            *(uint4*)(outHi + (size_t)d * DD + l15 * 8) = hh.q;
            *(uint4*)(outLo + (size_t)d * DD + l15 * 8) = ll.q;
        } else {
            float4 o0 = {o[0], o[1], o[2], o[3]};
            float4 o1 = {o[4], o[5], o[6], o[7]};
            float* op = outF + (size_t)d * DD + l15 * 8;
            *(float4*)op = o0;
            *(float4*)(op + 4) = o1;
        }
    }
}

// ---------------- launch ----------------
extern "C" void kernel_launch(void* const* d_in, const int* in_sizes, int n_in,
                              void* d_out, int out_size, void* d_ws, size_t ws_size,
                              hipStream_t stream) {
    const float* x    = (const float*)d_in[0];
    const float* Wl   = (const float*)d_in[1];
    const float* Wr   = (const float*)d_in[2];
    const float* att  = (const float*)d_in[3];
    const float* bias = (const float*)d_in[4];
    const int*   ei   = (const int*)d_in[5];

    int N = in_sizes[0] / DD;
    int E = in_sizes[5] / 2;
    const int* srcI = ei;
    const int* dstI = ei + E;
    float* out = (float*)d_out;
    int CB = (N + 127) >> 7;

    char* ws = (char*)d_ws;
    size_t off = 0;
    auto alloc = [&](size_t bytes) -> void* {
        void* p = ws + off;
        off += (bytes + 255) & ~(size_t)255;
        return p;
    };
    _Float16*       xl   = (_Float16*)alloc((size_t)N * DD * 2);
    _Float16*       xr   = (_Float16*)alloc((size_t)N * DD * 2);
    unsigned short* Ahi  = (unsigned short*)alloc((size_t)N * DD * 2);
    unsigned short* Alo  = (unsigned short*)alloc((size_t)N * DD * 2);
    unsigned short* Wth  = (unsigned short*)alloc((size_t)3 * 256 * 128 * 2);
    unsigned short* Wtl  = (unsigned short*)alloc((size_t)3 * 256 * 128 * 2);
    unsigned* part = (unsigned*)alloc((size_t)E * 4);
    int*   srcs    = (int*)alloc((size_t)E * 4);
    int*   row_ptr = (int*)alloc((size_t)(N + 1) * 4);
    int*   order   = (int*)alloc((size_t)N * 4);
    int*   baseC   = (int*)alloc((size_t)(CB + 1) * 4);
    // zero-block: histC[CB] | cursor0C[CB] | histD[128] | cursor0D[128]
    int*   z       = (int*)alloc((size_t)(2 * CB + 256) * 4);
    int*   histC    = z;
    int*   cursor0C = z + CB;
    int*   histD    = z + 2 * CB;
    int*   cursor0D = z + 2 * CB + 128;

    const int tb = 256;
    (void)hipMemsetAsync(z, 0, (size_t)(2 * CB + 256) * 4, stream);
    k_histC<<<640, 256, 0, stream>>>(dstI, histC, E, CB, Wl, Wr, Wth, Wtl);
    k_scanC2<<<1, 256, 0, stream>>>(histC, baseC, CB);
    k_part3<<<(E + CHUNK - 1) / CHUNK, 256, 0, stream>>>(srcI, dstI, baseC, cursor0C,
                                                         part, E, CB);
    k_part4<<<CB, 256, 0, stream>>>(part, baseC, srcs, row_ptr, N);
    int gD = (N + NCH - 1) / NCH;
    k_deghist<<<gD, 256, 0, stream>>>(row_ptr, histD, N);
    k_degpart<<<gD, 256, 0, stream>>>(row_ptr, histD, cursor0D, order, N);

    int gX = (N + 127) / 128;
    int NB = 16 * ((gX + 7) / 8);   // XCD-paired 1D grid (j and j+8 share an XCD)
    for (int L = 0; L < 3; ++L) {
        if (L == 0)
            k_gemm<1><<<NB, 256, 0, stream>>>(x, Ahi, Alo, Wth, Wtl, xl, xr, N, L, gX);
        else
            k_gemm<0><<<NB, 256, 0, stream>>>(x, Ahi, Alo, Wth, Wtl, xl, xr, N, L, gX);
        k_attn<<<((size_t)N * 16 + tb - 1) / tb, tb, 0, stream>>>(
            xl, xr, row_ptr, srcs, order, att + (size_t)L * DD, bias + (size_t)L * DD,
            out, Ahi, Alo, N, (L < 2) ? 1 : 0);
    }
}

// Round 11
// 463.462 us; speedup vs baseline: 1.3025x; 1.0215x over previous
//
#include <hip/hip_runtime.h>
#include <math.h>

#define DD 128
#define NEG 0.2f

typedef short short8 __attribute__((ext_vector_type(8)));
typedef float f32x4 __attribute__((ext_vector_type(4)));
typedef float f32x2 __attribute__((ext_vector_type(2)));
typedef _Float16 h2v __attribute__((ext_vector_type(2)));

__device__ __forceinline__ unsigned short f2bf(float f) {
    unsigned u = __float_as_uint(f);
    return (unsigned short)((u + 0x7fffu + ((u >> 16) & 1u)) >> 16);
}
__device__ __forceinline__ float bf2f(unsigned short h) {
    return __uint_as_float(((unsigned)h) << 16);
}

#if __has_builtin(__builtin_amdgcn_exp2f)
#define EXP2F(x) __builtin_amdgcn_exp2f(x)
#else
#define EXP2F(x) exp2f(x)
#endif

// ======================= CSR build =======================
// HW lessons: (r8) scattered device-scope atomics are memory-side 64B RMWs —
// LDS aggregation mandatory. (r9) scattered small stores suffer cross-XCD
// partial-line write amplification — LDS-staged contiguous write-out is
// load-bearing. (r10 accounting) deghist/degpart at NCH=8192 ran on 13 blocks
// (243 CUs idle, zero latency hiding) — the ~90us hidden cost since r3.
// This round: NCH 512 -> 196 blocks for the degree sort.

// exclusive scan in-place over sh[0..1024) (must be zero-padded), 256 threads.
__device__ void excl_scan_1024(int* sh, int* aux) {
    __syncthreads();
    int t = threadIdx.x;
    int base = t * 4;
    int a0 = sh[base], a1 = sh[base + 1], a2 = sh[base + 2], a3 = sh[base + 3];
    int s = a0 + a1 + a2 + a3;
    aux[t] = s;
    __syncthreads();
    for (int off = 1; off < 256; off <<= 1) {
        int v = (t >= off) ? aux[t - off] : 0;
        __syncthreads();
        aux[t] += v;
        __syncthreads();
    }
    int excl = aux[t] - s;
    sh[base] = excl;
    sh[base + 1] = excl + a0;
    sh[base + 2] = excl + a0 + a1;
    sh[base + 3] = excl + a0 + a1 + a2;
    __syncthreads();
}

// ---------------- fused: global dst-chunk histogram + weight cast ----------------
__global__ __launch_bounds__(256) void k_histC(const int* __restrict__ dst,
                                               int* __restrict__ histC, int E, int CB,
                                               const float* __restrict__ Wl,
                                               const float* __restrict__ Wr,
                                               unsigned short* __restrict__ Wth,
                                               unsigned short* __restrict__ Wtl) {
    __shared__ int h[1024];
    int t = threadIdx.x;
    if (blockIdx.x >= 256) {
        int idx = (blockIdx.x - 256) * 256 + t;
        if (idx < 3 * 256 * 128) {
            int L = idx >> 15;
            int rem = idx & 32767;
            int nn = rem >> 7;
            int k = rem & 127;
            float v = (nn < 128) ? Wl[L * 16384 + k * 128 + nn]
                                 : Wr[L * 16384 + k * 128 + (nn - 128)];
            unsigned short hh = f2bf(v);
            Wth[idx] = hh;
            Wtl[idx] = f2bf(v - bf2f(hh));
        }
        return;
    }
    for (int j = t; j < 1024; j += 256) h[j] = 0;
    __syncthreads();
    int stride = 256 * 256;
    for (int i = blockIdx.x * 256 + t; i < E; i += stride)
        atomicAdd(&h[dst[i] >> 7], 1);
    __syncthreads();
    for (int j = t; j < CB; j += 256)
        if (h[j]) atomicAdd(&histC[j], h[j]);
}

// ---------------- global scan of histC -> baseC (1 block) ----------------
__global__ __launch_bounds__(256) void k_scanC2(const int* __restrict__ histC,
                                                int* __restrict__ baseC, int CB) {
    __shared__ int sh[1024];
    __shared__ int aux[256];
    int t = threadIdx.x;
    for (int j = t; j < 1024; j += 256) sh[j] = (j < CB) ? histC[j] : 0;
    excl_scan_1024(sh, aux);
    for (int j = t; j <= CB; j += 256) baseC[j] = sh[j];
}

// ---------------- CSR partition pass 1 (staged, packed output) ----------------
#define CHUNK 4096
__global__ __launch_bounds__(256) void k_part3(const int* __restrict__ srcI,
                                               const int* __restrict__ dstI,
                                               const int* __restrict__ baseC,
                                               int* __restrict__ cursor0C,
                                               unsigned* __restrict__ part,
                                               int E, int CB) {
    __shared__ int sh[1024];
    __shared__ int aux[256];
    __shared__ int resBase[1024];
    __shared__ int cur[1024];
    __shared__ uint2 stage[CHUNK];
    int t = threadIdx.x;
    int c0 = blockIdx.x * CHUNK;
    int cnt = E - c0; if (cnt > CHUNK) cnt = CHUNK;

    for (int j = t; j < 1024; j += 256) sh[j] = 0;
    __syncthreads();
    for (int i = t; i < cnt; i += 256)
        atomicAdd(&sh[dstI[c0 + i] >> 7], 1);
    __syncthreads();
    for (int j = t; j < CB; j += 256) {
        int c = sh[j];
        resBase[j] = baseC[j] + (c ? atomicAdd(&cursor0C[j], c) : 0);
    }
    excl_scan_1024(sh, aux);            // leading barrier covers resBase reads
    for (int j = t; j < 1024; j += 256) cur[j] = sh[j];
    __syncthreads();
    for (int i = t; i < cnt; i += 256) {
        unsigned s = (unsigned)srcI[c0 + i];
        unsigned d = (unsigned)dstI[c0 + i];
        int b = (int)(d >> 7);
        int pos = atomicAdd(&cur[b], 1);
        stage[pos].x = s;
        stage[pos].y = d;
    }
    __syncthreads();
    // contiguous-per-bucket write-out (full-line bursts), packed to 4B
    for (int i = t; i < cnt; i += 256) {
        uint2 v = stage[i];
        int b = (int)(v.y >> 7);
        part[resBase[b] + (i - sh[b])] = v.x | ((v.y & 127u) << 25);
    }
}

// ---------------- CSR partition pass 2 (staged, packed input) ----------------
__global__ __launch_bounds__(256) void k_part4(const unsigned* __restrict__ part,
                                               const int* __restrict__ baseC,
                                               int* __restrict__ srcs,
                                               int* __restrict__ row_ptr,
                                               int N) {
    __shared__ int hist[128];
    __shared__ int incl[128];
    __shared__ int cur[128];
    __shared__ int srcS[4096];
    int b = blockIdx.x;
    int t = threadIdx.x;
    int base = baseC[b];
    int cnt = baseC[b + 1] - base;
    int node0 = b << 7;

    if (t < 128) hist[t] = 0;
    __syncthreads();
    for (int i = t; i < cnt; i += 256)
        atomicAdd(&hist[part[base + i] >> 25], 1);
    __syncthreads();
    if (t < 128) incl[t] = hist[t];
    __syncthreads();
    for (int off = 1; off < 128; off <<= 1) {
        int v = 0;
        if (t < 128 && t >= off) v = incl[t - off];
        __syncthreads();
        if (t < 128) incl[t] += v;
        __syncthreads();
    }
    if (t < 128) cur[t] = incl[t] - hist[t];
    __syncthreads();
    for (int i = t; i < cnt; i += 256) {
        unsigned v = part[base + i];
        int r = atomicAdd(&cur[v >> 25], 1);
        if (r < 4096) srcS[r] = (int)(v & 0x1FFFFFFu);
    }
    __syncthreads();
    for (int i = t; i < cnt; i += 256)
        srcs[base + i] = srcS[i];
    int nodes = N - node0; if (nodes > 128) nodes = 128;
    if (t < nodes) row_ptr[node0 + t + 1] = base + incl[t];
    if (b == 0 && t == 0) row_ptr[0] = 0;
}

// ---------------- degree-bucket sort of dst nodes (LDS-hist) ----------------
// r11: NCH 8192 -> 512 (13 -> 196 blocks). The old 13-block config left 243
// CUs idle with zero latency hiding — the dominant hidden cost since r3.
#define NCH 512
__global__ __launch_bounds__(256) void k_deghist(const int* __restrict__ row_ptr,
                                                 int* __restrict__ histD, int N) {
    __shared__ int h[128];
    int t = threadIdx.x;
    if (t < 128) h[t] = 0;
    __syncthreads();
    int c0 = blockIdx.x * NCH;
    int cnt = N - c0; if (cnt > NCH) cnt = NCH;
    for (int i = t; i < cnt; i += 256) {
        int deg = row_ptr[c0 + i + 1] - row_ptr[c0 + i];
        int c = deg < 127 ? deg : 127;
        atomicAdd(&h[c], 1);
    }
    __syncthreads();
    if (t < 128 && h[t]) atomicAdd(&histD[t], h[t]);
}

__global__ __launch_bounds__(256) void k_degpart(const int* __restrict__ row_ptr,
                                                 const int* __restrict__ histD,
                                                 int* __restrict__ cursor0D,
                                                 int* __restrict__ order, int N) {
    __shared__ int hist[128];
    __shared__ int gex[128];
    __shared__ int excl[128];
    __shared__ int cur[128];
    __shared__ int resB[128];
    __shared__ int stage[NCH];
    int t = threadIdx.x;
    int c0 = blockIdx.x * NCH;
    int cnt = N - c0; if (cnt > NCH) cnt = NCH;

    int g0 = 0;
    if (t < 128) { hist[t] = 0; g0 = histD[t]; gex[t] = g0; }
    __syncthreads();
    for (int i = t; i < cnt; i += 256) {
        int deg = row_ptr[c0 + i + 1] - row_ptr[c0 + i];
        int c = deg < 127 ? deg : 127;
        atomicAdd(&hist[c], 1);
    }
    __syncthreads();
    for (int off = 1; off < 128; off <<= 1) {
        int v = 0;
        if (t < 128 && t >= off) v = gex[t - off];
        __syncthreads();
        if (t < 128) gex[t] += v;
        __syncthreads();
    }
    if (t < 128) resB[t] = (gex[t] - g0) + (hist[t] ? atomicAdd(&cursor0D[t], hist[t]) : 0);
    if (t < 128) excl[t] = hist[t];
    __syncthreads();
    for (int off = 1; off < 128; off <<= 1) {
        int v = 0;
        if (t < 128 && t >= off) v = excl[t - off];
        __syncthreads();
        if (t < 128) excl[t] += v;
        __syncthreads();
    }
    if (t < 128) { excl[t] -= hist[t]; cur[t] = excl[t]; }
    __syncthreads();
    for (int i = t; i < cnt; i += 256) {
        int deg = row_ptr[c0 + i + 1] - row_ptr[c0 + i];
        int c = deg < 127 ? deg : 127;
        int p = atomicAdd(&cur[c], 1);
        stage[p] = (c << 20) | (c0 + i);   // N < 2^20
    }
    __syncthreads();
    for (int i = t; i < cnt; i += 256) {
        int v = stage[i];
        int c = v >> 20;
        order[resB[c] + (i - excl[c])] = v & 0xFFFFF;
    }
}

// ---------------- MFMA GEMM: [xl|xr][M,128each] = A[M,128] @ W[128,256] ----------------
// Proven LDS structure + T14 prefetch; XCD-paired 1D grid; F32SRC=1 stages
// layer 0 directly from x (f32) with in-register hi/lo split.
__device__ __forceinline__ void cvt8(const float4& a, const float4& b, uint4& hi, uint4& lo) {
    union US8 { unsigned short s[8]; uint4 u; } H, Lo;
    float f[8] = {a.x, a.y, a.z, a.w, b.x, b.y, b.z, b.w};
#pragma unroll
    for (int i = 0; i < 8; i++) {
        unsigned short h = f2bf(f[i]);
        H.s[i] = h;
        Lo.s[i] = f2bf(f[i] - bf2f(h));
    }
    hi = H.u; lo = Lo.u;
}

template <int F32SRC>
__global__ __launch_bounds__(256) void k_gemm(const float* __restrict__ Xf,
                                              const unsigned short* __restrict__ Ahi,
                                              const unsigned short* __restrict__ Alo,
                                              const unsigned short* __restrict__ Wth,
                                              const unsigned short* __restrict__ Wtl,
                                              _Float16* __restrict__ xl, _Float16* __restrict__ xr,
                                              int M, int L, int gX) {
    __shared__ unsigned short sA[2][128][40];
    __shared__ unsigned short sB[2][128][40];
    int b = blockIdx.x;
    int grp = b >> 4, j8 = b & 7, half = (b >> 3) & 1;
    int ry = grp * 8 + j8;
    if (ry >= gX) return;

    int t = threadIdx.x;
    int lane = t & 63;
    int l15 = lane & 15;
    int quad = lane >> 4;
    int wave = t >> 6;
    int wm = wave & 1;
    int wn = wave >> 1;
    int r0 = ry * 128;
    const unsigned short* WthL = Wth + ((size_t)L * 256 + half * 128) * 128;
    const unsigned short* WtlL = Wtl + ((size_t)L * 256 + half * 128) * 128;

    int row0 = t >> 2,       row1 = (t + 256) >> 2;
    int kq   = (t & 3) * 8;
    int gr0 = r0 + row0; gr0 = gr0 < M ? gr0 : M - 1;
    int gr1 = r0 + row1; gr1 = gr1 < M ? gr1 : M - 1;

    uint4 rAh0, rAh1, rAl0, rAl1, rBh0, rBh1, rBl0, rBl1;
    float4 f00, f01, f10, f11;

#define GLOADA(K0)                                                          \
    if (F32SRC) {                                                           \
        f00 = *(const float4*)(Xf + (size_t)gr0 * DD + (K0) + kq);          \
        f01 = *(const float4*)(Xf + (size_t)gr0 * DD + (K0) + kq + 4);      \
        f10 = *(const float4*)(Xf + (size_t)gr1 * DD + (K0) + kq);          \
        f11 = *(const float4*)(Xf + (size_t)gr1 * DD + (K0) + kq + 4);      \
    } else {                                                                \
        rAh0 = *(const uint4*)(Ahi + (size_t)gr0 * DD + (K0) + kq);         \
        rAh1 = *(const uint4*)(Ahi + (size_t)gr1 * DD + (K0) + kq);         \
        rAl0 = *(const uint4*)(Alo + (size_t)gr0 * DD + (K0) + kq);         \
        rAl1 = *(const uint4*)(Alo + (size_t)gr1 * DD + (K0) + kq);         \
    }
#define GLOADB(K0)                                                          \
    rBh0 = *(const uint4*)(WthL + (size_t)row0 * DD + (K0) + kq);           \
    rBh1 = *(const uint4*)(WthL + (size_t)row1 * DD + (K0) + kq);           \
    rBl0 = *(const uint4*)(WtlL + (size_t)row0 * DD + (K0) + kq);           \
    rBl1 = *(const uint4*)(WtlL + (size_t)row1 * DD + (K0) + kq);

    f32x4 acc[4][4] = {};
    union F8 { short8 v; uint4 u; };

    GLOADA(0);
    GLOADB(0);

#pragma unroll
    for (int kc = 0; kc < 4; kc++) {
        if (kc) __syncthreads();
        if (F32SRC) {
            cvt8(f00, f01, rAh0, rAl0);
            cvt8(f10, f11, rAh1, rAl1);
        }
        *(uint4*)&sA[0][row0][kq] = rAh0;
        *(uint4*)&sA[0][row1][kq] = rAh1;
        *(uint4*)&sA[1][row0][kq] = rAl0;
        *(uint4*)&sA[1][row1][kq] = rAl1;
        *(uint4*)&sB[0][row0][kq] = rBh0;
        *(uint4*)&sB[0][row1][kq] = rBh1;
        *(uint4*)&sB[1][row0][kq] = rBl0;
        *(uint4*)&sB[1][row1][kq] = rBl1;
        __syncthreads();
        if (kc < 3) { GLOADA((kc + 1) * 32); GLOADB((kc + 1) * 32); }  // T14

        F8 ah[4], al[4], bh[4], bl[4];
#pragma unroll
        for (int mt = 0; mt < 4; mt++) {
            ah[mt].u = *(const uint4*)&sA[0][wm * 64 + mt * 16 + l15][quad * 8];
            al[mt].u = *(const uint4*)&sA[1][wm * 64 + mt * 16 + l15][quad * 8];
        }
#pragma unroll
        for (int nt = 0; nt < 4; nt++) {
            bh[nt].u = *(const uint4*)&sB[0][wn * 64 + nt * 16 + l15][quad * 8];
            bl[nt].u = *(const uint4*)&sB[1][wn * 64 + nt * 16 + l15][quad * 8];
        }
#pragma unroll
        for (int mt = 0; mt < 4; mt++)
#pragma unroll
            for (int nt = 0; nt < 4; nt++) {
                acc[mt][nt] = __builtin_amdgcn_mfma_f32_16x16x32_bf16(ah[mt].v, bh[nt].v, acc[mt][nt], 0, 0, 0);
                acc[mt][nt] = __builtin_amdgcn_mfma_f32_16x16x32_bf16(al[mt].v, bh[nt].v, acc[mt][nt], 0, 0, 0);
                acc[mt][nt] = __builtin_amdgcn_mfma_f32_16x16x32_bf16(ah[mt].v, bl[nt].v, acc[mt][nt], 0, 0, 0);
            }
    }
#undef GLOADA
#undef GLOADB

    _Float16* C = half ? xr : xl;
#pragma unroll
    for (int mt = 0; mt < 4; mt++)
#pragma unroll
        for (int r = 0; r < 4; r++) {
            int row = r0 + wm * 64 + mt * 16 + quad * 4 + r;
            if (row < M) {
#pragma unroll
                for (int nt = 0; nt < 4; nt++)
                    C[(size_t)row * DD + wn * 64 + nt * 16 + l15] = (_Float16)acc[mt][nt][r];
            }
        }
}

// ---------------- fused per-dst attention + aggregate ----------------
// NOTE (r5/r6): pinned at random-gather cache bandwidth (~3.6 TB/s TCC);
// multiple structural variants all land at ~70us with FETCH ~200MB. Frozen.
__global__ __launch_bounds__(256) void k_attn(const _Float16* __restrict__ xl,
                                              const _Float16* __restrict__ xr,
                                              const int* __restrict__ row_ptr,
                                              const int* __restrict__ srcs,
                                              const int* __restrict__ order,
                                              const float* __restrict__ att,
                                              const float* __restrict__ bias,
                                              float* __restrict__ outF,
                                              unsigned short* __restrict__ outHi,
                                              unsigned short* __restrict__ outLo,
                                              int n, int mode) {
    int wid = (blockIdx.x * blockDim.x + threadIdx.x) >> 6;
    int l = threadIdx.x & 63;
    int l15 = l & 15;
    int g = l >> 4;
    int idx = wid * 4 + g;
    bool act = idx < n;
    int d = act ? order[idx] : 0;

    union Q { uint4 q; h2v h[4]; };
    const float LOG2E = 1.44269504088896f;

    h2v at[4], xrh[4];
    {
        float4 a0 = *(const float4*)(att + l15 * 8);
        float4 a1 = *(const float4*)(att + l15 * 8 + 4);
        at[0] = h2v{(_Float16)(a0.x * LOG2E), (_Float16)(a0.y * LOG2E)};
        at[1] = h2v{(_Float16)(a0.z * LOG2E), (_Float16)(a0.w * LOG2E)};
        at[2] = h2v{(_Float16)(a1.x * LOG2E), (_Float16)(a1.y * LOG2E)};
        at[3] = h2v{(_Float16)(a1.z * LOG2E), (_Float16)(a1.w * LOG2E)};
        Q hr; hr.q = *(const uint4*)(xr + (size_t)d * DD + l15 * 8);
#pragma unroll
        for (int j = 0; j < 4; j++) xrh[j] = hr.h[j];
    }
    const _Float16 cneg = (_Float16)NEG;

    int beg = act ? row_ptr[d] : 0;
    int end = act ? row_ptr[d + 1] : 0;
    int cnt = end - beg;

    int mc = cnt;
    mc = max(mc, __shfl_xor(mc, 16, 64));
    mc = max(mc, __shfl_xor(mc, 32, 64));
    int iters = (mc + 3) >> 2;

    float lse = 0.f;
    float av[8] = {};

    int i0 = beg, i1 = beg + 1, i2 = beg + 2, i3 = beg + 3;
    bool v0 = i0 < end, v1 = i1 < end, v2 = i2 < end, v3 = i3 < end;
    int s0 = v0 ? srcs[i0] : 0;
    int s1 = v1 ? srcs[i1] : 0;
    int s2 = v2 ? srcs[i2] : 0;
    int s3 = v3 ? srcs[i3] : 0;

    const _Float16* xlp = xl + l15 * 8;

    for (int it = 0; it < iters; ++it) {
        Q h0, h1, h2, h3;
        h0.q = *(const uint4*)(xlp + (size_t)s0 * DD);
        h1.q = *(const uint4*)(xlp + (size_t)s1 * DD);
        h2.q = *(const uint4*)(xlp + (size_t)s2 * DD);
        h3.q = *(const uint4*)(xlp + (size_t)s3 * DD);
        int n0 = i0 + 4, n1 = i1 + 4, n2 = i2 + 4, n3 = i3 + 4;
        bool nv0 = n0 < end, nv1 = n1 < end, nv2 = n2 < end, nv3 = n3 < end;
        int t0 = nv0 ? srcs[n0] : 0;
        int t1 = nv1 ? srcs[n1] : 0;
        int t2 = nv2 ? srcs[n2] : 0;
        int t3 = nv3 ? srcs[n3] : 0;

        float p0 = 0.f, p1 = 0.f, p2 = 0.f, p3 = 0.f;
#pragma unroll
        for (int j = 0; j < 4; j++) {
            h2v z0 = h0.h[j] + xrh[j];
            h2v zl0 = __builtin_elementwise_max(z0, z0 * cneg);
            p0 = __builtin_amdgcn_fdot2(zl0, at[j], p0, false);
            h2v z1 = h1.h[j] + xrh[j];
            h2v zl1 = __builtin_elementwise_max(z1, z1 * cneg);
            p1 = __builtin_amdgcn_fdot2(zl1, at[j], p1, false);
            h2v z2 = h2.h[j] + xrh[j];
            h2v zl2 = __builtin_elementwise_max(z2, z2 * cneg);
            p2 = __builtin_amdgcn_fdot2(zl2, at[j], p2, false);
            h2v z3 = h3.h[j] + xrh[j];
            h2v zl3 = __builtin_elementwise_max(z3, z3 * cneg);
            p3 = __builtin_amdgcn_fdot2(zl3, at[j], p3, false);
        }
        p0 += __shfl_xor(p0, 1, 64);  p1 += __shfl_xor(p1, 1, 64);
        p2 += __shfl_xor(p2, 1, 64);  p3 += __shfl_xor(p3, 1, 64);
        p0 += __shfl_xor(p0, 2, 64);  p1 += __shfl_xor(p1, 2, 64);
        p2 += __shfl_xor(p2, 2, 64);  p3 += __shfl_xor(p3, 2, 64);
        p0 += __shfl_xor(p0, 4, 64);  p1 += __shfl_xor(p1, 4, 64);
        p2 += __shfl_xor(p2, 4, 64);  p3 += __shfl_xor(p3, 4, 64);
        p0 += __shfl_xor(p0, 8, 64);  p1 += __shfl_xor(p1, 8, 64);
        p2 += __shfl_xor(p2, 8, 64);  p3 += __shfl_xor(p3, 8, 64);
        p0 = fminf(fmaxf(p0, -86.f), 86.f);
        p1 = fminf(fmaxf(p1, -86.f), 86.f);
        p2 = fminf(fmaxf(p2, -86.f), 86.f);
        p3 = fminf(fmaxf(p3, -86.f), 86.f);
        float w0 = v0 ? EXP2F(p0) : 0.f;
        float w1 = v1 ? EXP2F(p1) : 0.f;
        float w2 = v2 ? EXP2F(p2) : 0.f;
        float w3 = v3 ? EXP2F(p3) : 0.f;
        lse += (w0 + w1) + (w2 + w3);
#pragma unroll
        for (int j = 0; j < 4; j++) {
            av[2 * j]     += (float)h0.h[j][0] * w0;
            av[2 * j + 1] += (float)h0.h[j][1] * w0;
            av[2 * j]     += (float)h1.h[j][0] * w1;
            av[2 * j + 1] += (float)h1.h[j][1] * w1;
            av[2 * j]     += (float)h2.h[j][0] * w2;
            av[2 * j + 1] += (float)h2.h[j][1] * w2;
            av[2 * j]     += (float)h3.h[j][0] * w3;
            av[2 * j + 1] += (float)h3.h[j][1] * w3;
        }
        i0 = n0; i1 = n1; i2 = n2; i3 = n3;
        v0 = nv0; v1 = nv1; v2 = nv2; v3 = nv3;
        s0 = t0; s1 = t1; s2 = t2; s3 = t3;
    }

    if (act) {
        float inv = (cnt > 0) ? 1.0f / lse : 0.f;
        float o[8];
        float4 b0 = *(const float4*)(bias + l15 * 8);
        float4 b1 = *(const float4*)(bias + l15 * 8 + 4);
        float bv[8] = {b0.x, b0.y, b0.z, b0.w, b1.x, b1.y, b1.z, b1.w};
#pragma unroll
        for (int j = 0; j < 8; j++) o[j] = av[j] * inv + bv[j];
        if (mode) {
            union U8 { unsigned short s[8]; uint4 q; };
            U8 hh, ll;
#pragma unroll
            for (int j = 0; j < 8; j++) {
                float v = fmaxf(o[j], 0.f);
                hh.s[j] = f2bf(v);
                ll.s[j] = f2bf(v - bf2f(hh.s[j]));
            }
            *(uint4*)(outHi + (size_t)d * DD + l15 * 8) = hh.q;
            *(uint4*)(outLo + (size_t)d * DD + l15 * 8) = ll.q;
        } else {
            float4 o0 = {o[0], o[1], o[2], o[3]};
            float4 o1 = {o[4], o[5], o[6], o[7]};
            float* op = outF + (size_t)d * DD + l15 * 8;
            *(float4*)op = o0;
            *(float4*)(op + 4) = o1;
        }
    }
}

// ---------------- launch ----------------
extern "C" void kernel_launch(void* const* d_in, const int* in_sizes, int n_in,
                              void* d_out, int out_size, void* d_ws, size_t ws_size,
                              hipStream_t stream) {
    const float* x    = (const float*)d_in[0];
    const float* Wl   = (const float*)d_in[1];
    const float* Wr   = (const float*)d_in[2];
    const float* att  = (const float*)d_in[3];
    const float* bias = (const float*)d_in[4];
    const int*   ei   = (const int*)d_in[5];

    int N = in_sizes[0] / DD;
    int E = in_sizes[5] / 2;
    const int* srcI = ei;
    const int* dstI = ei + E;
    float* out = (float*)d_out;
    int CB = (N + 127) >> 7;

    char* ws = (char*)d_ws;
    size_t off = 0;
    auto alloc = [&](size_t bytes) -> void* {
        void* p = ws + off;
        off += (bytes + 255) & ~(size_t)255;
        return p;
    };
    _Float16*       xl   = (_Float16*)alloc((size_t)N * DD * 2);
    _Float16*       xr   = (_Float16*)alloc((size_t)N * DD * 2);
    unsigned short* Ahi  = (unsigned short*)alloc((size_t)N * DD * 2);
    unsigned short* Alo  = (unsigned short*)alloc((size_t)N * DD * 2);
    unsigned short* Wth  = (unsigned short*)alloc((size_t)3 * 256 * 128 * 2);
    unsigned short* Wtl  = (unsigned short*)alloc((size_t)3 * 256 * 128 * 2);
    unsigned* part = (unsigned*)alloc((size_t)E * 4);
    int*   srcs    = (int*)alloc((size_t)E * 4);
    int*   row_ptr = (int*)alloc((size_t)(N + 1) * 4);
    int*   order   = (int*)alloc((size_t)N * 4);
    int*   baseC   = (int*)alloc((size_t)(CB + 1) * 4);
    // zero-block: histC[CB] | cursor0C[CB] | histD[128] | cursor0D[128]
    int*   z       = (int*)alloc((size_t)(2 * CB + 256) * 4);
    int*   histC    = z;
    int*   cursor0C = z + CB;
    int*   histD    = z + 2 * CB;
    int*   cursor0D = z + 2 * CB + 128;

    const int tb = 256;
    (void)hipMemsetAsync(z, 0, (size_t)(2 * CB + 256) * 4, stream);
    k_histC<<<640, 256, 0, stream>>>(dstI, histC, E, CB, Wl, Wr, Wth, Wtl);
    k_scanC2<<<1, 256, 0, stream>>>(histC, baseC, CB);
    k_part3<<<(E + CHUNK - 1) / CHUNK, 256, 0, stream>>>(srcI, dstI, baseC, cursor0C,
                                                         part, E, CB);
    k_part4<<<CB, 256, 0, stream>>>(part, baseC, srcs, row_ptr, N);
    int gD = (N + NCH - 1) / NCH;
    k_deghist<<<gD, 256, 0, stream>>>(row_ptr, histD, N);
    k_degpart<<<gD, 256, 0, stream>>>(row_ptr, histD, cursor0D, order, N);

    int gX = (N + 127) / 128;
    int NB = 16 * ((gX + 7) / 8);   // XCD-paired 1D grid (j and j+8 share an XCD)
    for (int L = 0; L < 3; ++L) {
        if (L == 0)
            k_gemm<1><<<NB, 256, 0, stream>>>(x, Ahi, Alo, Wth, Wtl, xl, xr, N, L, gX);
        else
            k_gemm<0><<<NB, 256, 0, stream>>>(x, Ahi, Alo, Wth, Wtl, xl, xr, N, L, gX);
        k_attn<<<((size_t)N * 16 + tb - 1) / tb, tb, 0, stream>>>(
            xl, xr, row_ptr, srcs, order, att + (size_t)L * DD, bias + (size_t)L * DD,
            out, Ahi, Alo, N, (L < 2) ? 1 : 0);
    }
}